// Round 6
// baseline (1279.571 us; speedup 1.0000x reference)
//
#include <hip/hip_runtime.h>
#include <hip/hip_bf16.h>

#define NN 10000
#define NE 50000
#define MAXDEG 32

typedef __attribute__((ext_vector_type(8))) short bfrag8;  // 8 bf16 = 4 VGPR (MFMA A/B)
typedef __attribute__((ext_vector_type(4))) short s16x4;   // 4 bf16 = b64 store
typedef __attribute__((ext_vector_type(8))) short s16x8;   // 8 bf16 = b128 store
typedef __attribute__((ext_vector_type(4))) float f32x4;   // MFMA C/D

__device__ __forceinline__ float silu_f(float v){ return v / (1.0f + __expf(-v)); }
__device__ __forceinline__ short f2b(float f){           // f32 -> bf16 RNE
  unsigned u = __float_as_uint(f);
  u += 0x7fffu + ((u>>16)&1u);
  return (short)(u>>16);
}
__device__ __forceinline__ float b2f(short s){
  return __uint_as_float(((unsigned)(unsigned short)s)<<16);
}
// async global->LDS: per-lane global addr, wave-uniform LDS base, lane*16 dest
__device__ __forceinline__ void gload_lds16(const void* g, void* l){
  __builtin_amdgcn_global_load_lds(
      (const __attribute__((address_space(1))) void*)g,
      (__attribute__((address_space(3))) void*)l, 16, 0, 0);
}

// ---------------- K0: hT[n][c][j] = bf16(rmsnorm(x)) transposed+swizzled ----------------
__global__ __launch_bounds__(256) void k_rms1(const float* __restrict__ x,
                                              const float* __restrict__ gamma,
                                              short* __restrict__ hT){
  int idx = blockIdx.x*256 + threadIdx.x;
  if (idx >= NN*64) return;
  int n = idx>>6, c = idx&63;
  const float* xp = x + (size_t)n*1600 + c;
  float v[25]; float ss = 0.f;
#pragma unroll
  for (int i=0;i<25;i++){ v[i] = xp[i*64]; ss += v[i]*v[i]; }
  float inv = gamma[c] * rsqrtf(ss*(1.f/25.f) + 1e-6f);
  short* hp = hT + (size_t)n*2048 + c*32;
  const int sw = (c>>1)&3;
#pragma unroll
  for (int s=0;s<4;s++){
    s16x8 o;
#pragma unroll
    for (int k=0;k<8;k++){
      int j = s*8 + k;
      o[k] = (j<25) ? f2b(v[j]*inv) : (short)0;
    }
    *(s16x8*)(hp + ((s ^ sw)<<3)) = o;
  }
}

// ------------- Kprep: weights -> MFMA bf16 layouts -------------
__global__ void k_wprep(const float* __restrict__ W1, const float* __restrict__ tog,
                        const float* __restrict__ fromg, const float* __restrict__ proj,
                        const float* __restrict__ fw1, const float* __restrict__ fw2,
                        const float* __restrict__ rw1, const float* __restrict__ rw2,
                        const float* __restrict__ rw3, const float* __restrict__ w0e,
                        short* __restrict__ w1t, short* __restrict__ togA,
                        short* __restrict__ fgA, short* __restrict__ projT,
                        short* __restrict__ fw1T, short* __restrict__ fw2T,
                        short* __restrict__ rw1T, short* __restrict__ rw2T,
                        short* __restrict__ rw3T, short* __restrict__ w0eT){
  int t0 = blockIdx.x*blockDim.x + threadIdx.x;
  int stride = gridDim.x*blockDim.x;
  for (int idx=t0; idx<64*136; idx+=stride){
    int hh = idx/136, k = idx-136*hh;
    w1t[idx] = (k<128) ? f2b(W1[k*64+hh]) : (short)0;
  }
  for (int idx=t0; idx<48*40; idx+=stride){
    int g = idx/40, i = idx-40*g;
    togA[idx] = (g<36 && i<25) ? f2b(tog[g*25+i]) : (short)0;
  }
  for (int idx=t0; idx<32*72; idx+=stride){
    int j = idx/72, g = idx-72*j;
    fgA[idx] = (j<25 && g<36) ? f2b(fromg[j*36+g]) : (short)0;
  }
  for (int idx=t0; idx<64*64; idx+=stride){   // projT[c][k] = proj[k][c]
    int c = idx>>6, k = idx&63;
    projT[idx] = f2b(proj[k*64+c]);
  }
  for (int idx=t0; idx<128*64; idx+=stride){  // fw1T[f][c] = fw1[c][f]
    int f = idx>>6, c = idx&63;
    fw1T[idx] = f2b(fw1[c*128+f]);
  }
  for (int idx=t0; idx<64*128; idx+=stride){  // fw2T[c][f] = fw2[f][c]
    int c = idx>>7, f = idx&127;
    fw2T[idx] = f2b(fw2[f*64+c]);
  }
  for (int idx=t0; idx<64*96; idx+=stride){   // rw1T[n][k] = rw1[k][n]
    int n = idx/96, k = idx-96*n;
    rw1T[idx] = f2b(rw1[k*64+n]);
  }
  for (int idx=t0; idx<64*64; idx+=stride){   // rw2T[n][k] = rw2[k][n]
    int n = idx>>6, k = idx&63;
    rw2T[idx] = f2b(rw2[k*64+n]);
  }
  for (int idx=t0; idx<640*64; idx+=stride){  // rw3T[n][k] = rw3[k][n]
    int n = idx>>6, k = idx&63;
    rw3T[idx] = f2b(rw3[(size_t)k*640+n]);
  }
  for (int idx=t0; idx<192*128; idx+=stride){ // w0eT[m][c] = w0e[c][m]
    int m = idx>>7, c = idx&127;
    w0eT[idx] = f2b(w0e[c*192+m]);
  }
}

// ------------- Kfill: CSR-lite by dst -------------
__global__ __launch_bounds__(256) void k_fill(const int* __restrict__ ei,
                                              int* __restrict__ cnt,
                                              unsigned short* __restrict__ eidTab){
  int e = blockIdx.x*256 + threadIdx.x;
  if (e >= NE) return;
  int dst = ei[NE+e];
  int pos = atomicAdd(&cnt[dst], 1);
  if (pos < MAXDEG) eidTab[dst*MAXDEG + pos] = (unsigned short)e;
}

// ---------------- K1: radial MLP, MFMA, 32 edges/block ----------------
__global__ __launch_bounds__(256,4) void k_radial(
  const int* __restrict__ ei, const int* __restrict__ an,
  const float* __restrict__ edist,
  const float* __restrict__ stab, const float* __restrict__ ttab,
  const short* __restrict__ rw1T, const float* __restrict__ rb1,
  const short* __restrict__ rw2T, const float* __restrict__ rb2,
  const short* __restrict__ rw3T, const float* __restrict__ rb3,
  short* __restrict__ rfS)
{
  __shared__ __align__(16) short SP[7936];
  const int tid = threadIdx.x;
  const int wv = tid>>6, lane = tid&63, lo = lane&15, q = lane>>4;
  const int e0 = blockIdx.x*32;
  {
    int e = tid>>3;
    int ee = min(e0+e, NE-1);
    int srcE = ei[ee], dstE = ei[NE+ee];
    const float* dp = edist + (size_t)ee*32;
    const float* sp = stab + (size_t)an[srcE]*32;
    const float* tp = ttab + (size_t)an[dstE]*32;
    int kb = tid&7;
#pragma unroll
    for (int it=0; it<12; ++it){
      int k = kb + it*8;
      float v = (k<32) ? dp[k] : (k<64 ? sp[k-32] : tp[k-64]);
      SP[e*104+k] = f2b(v);
    }
  }
  __syncthreads();
  {
    f32x4 zf={0.f,0.f,0.f,0.f}; f32x4 acc[2]={zf,zf};
#pragma unroll
    for (int kt=0;kt<3;kt++){
      bfrag8 a = *(const bfrag8*)&rw1T[(wv*16+lo)*96 + kt*32 + q*8];
#pragma unroll
      for (int et=0;et<2;et++){
        bfrag8 b = *(const bfrag8*)&SP[(et*16+lo)*104 + kt*32 + q*8];
        acc[et] = __builtin_amdgcn_mfma_f32_16x16x32_bf16(a,b,acc[et],0,0,0);
      }
    }
    int n1 = wv*16 + q*4;
    const float4 bb = *(const float4*)&rb1[n1];
#pragma unroll
    for (int et=0;et<2;et++){
      s16x4 o;
      o[0]=f2b(silu_f(acc[et][0]+bb.x)); o[1]=f2b(silu_f(acc[et][1]+bb.y));
      o[2]=f2b(silu_f(acc[et][2]+bb.z)); o[3]=f2b(silu_f(acc[et][3]+bb.w));
      *(s16x4*)&SP[3328 + (et*16+lo)*72 + n1] = o;
    }
  }
  __syncthreads();
  {
    f32x4 zf={0.f,0.f,0.f,0.f}; f32x4 acc[2]={zf,zf};
#pragma unroll
    for (int kt=0;kt<2;kt++){
      bfrag8 a = *(const bfrag8*)&rw2T[(wv*16+lo)*64 + kt*32 + q*8];
#pragma unroll
      for (int et=0;et<2;et++){
        bfrag8 b = *(const bfrag8*)&SP[3328 + (et*16+lo)*72 + kt*32 + q*8];
        acc[et] = __builtin_amdgcn_mfma_f32_16x16x32_bf16(a,b,acc[et],0,0,0);
      }
    }
    int n2 = wv*16 + q*4;
    const float4 bb = *(const float4*)&rb2[n2];
#pragma unroll
    for (int et=0;et<2;et++){
      s16x4 o;
      o[0]=f2b(silu_f(acc[et][0]+bb.x)); o[1]=f2b(silu_f(acc[et][1]+bb.y));
      o[2]=f2b(silu_f(acc[et][2]+bb.z)); o[3]=f2b(silu_f(acc[et][3]+bb.w));
      *(s16x4*)&SP[5632 + (et*16+lo)*72 + n2] = o;
    }
  }
  __syncthreads();
  {
    bfrag8 bfr[2][2];
#pragma unroll
    for (int et=0;et<2;et++)
#pragma unroll
      for (int kt=0;kt<2;kt++)
        bfr[et][kt] = *(const bfrag8*)&SP[5632 + (et*16+lo)*72 + kt*32 + q*8];
    for (int mi=0; mi<10; ++mi){
      int n3base = (wv + mi*4)*16;
      f32x4 zf={0.f,0.f,0.f,0.f}; f32x4 acc[2]={zf,zf};
#pragma unroll
      for (int kt=0;kt<2;kt++){
        bfrag8 a = *(const bfrag8*)&rw3T[(size_t)(n3base+lo)*64 + kt*32 + q*8];
        acc[0] = __builtin_amdgcn_mfma_f32_16x16x32_bf16(a,bfr[0][kt],acc[0],0,0,0);
        acc[1] = __builtin_amdgcn_mfma_f32_16x16x32_bf16(a,bfr[1][kt],acc[1],0,0,0);
      }
      int n3 = n3base + q*4;
      const float4 bb = *(const float4*)&rb3[n3];
#pragma unroll
      for (int et=0;et<2;et++){
        int e = e0 + et*16 + lo;
        if (e < NE){
          s16x4 o;
          o[0]=f2b(acc[et][0]+bb.x); o[1]=f2b(acc[et][1]+bb.y);
          o[2]=f2b(acc[et][2]+bb.z); o[3]=f2b(acc[et][3]+bb.w);
          *(s16x4*)&rfS[(size_t)e*640 + n3] = o;
        }
      }
    }
  }
}

// ---------------- K3: per-DST edge kernel — loops incoming edges, NO atomics ----------------
// LDS shorts: srcH [0,2048) staged/edge; dstH [2048,4096) staged once;
//   xeB[32][136]/sg[64][72] @ [4096,8704) (zeroed at start; pads never read);
//   msgs/msg2 [64][40] @ [8704,11264)  (wigL f32[625] aliases [8704,9954) — consumed
//   into VGPR frags before msgs written; stale shorts land only in never-read cols 32..39);
//   gateL f32[64] @ sh 11264, ahead f32[8] @ 11392, dsum f32[8] @ 11408. Total 22848 B.
__global__ __launch_bounds__(256,6) void k_edge(
  const short* __restrict__ hT, const int* __restrict__ ei,
  const float* __restrict__ wig,
  const int* __restrict__ cnt, const unsigned short* __restrict__ eidTab,
  const short* __restrict__ w1t, const short* __restrict__ togA,
  const short* __restrict__ fgA, const short* __restrict__ w0eT,
  const float* __restrict__ adot,
  const short* __restrict__ rfS, float* __restrict__ agg)
{
  __shared__ __align__(16) short SH[11424];
  float* wigL  = (float*)&SH[8704];
  float* gateL = (float*)&SH[11264];
  float* ahead = (float*)&SH[11392];
  float* dsum  = (float*)&SH[11408];
  const int tid = threadIdx.x;
  const int wv = tid>>6, lane = tid&63, lo = lane&15, q = lane>>4;
  const int n = blockIdx.x;
  const int deg = min(cnt[n], MAXDEG);
  const bfrag8 wz = {0,0,0,0,0,0,0,0};

  // zero xeB/sg region + dsum (uninit-LDS NaN protection)
  {
    const s16x4 z4 = {0,0,0,0};
    for (int idx=tid; idx<1152; idx+=256) *(s16x4*)&SH[4096 + idx*4] = z4;
    if (tid < 8) dsum[tid] = 0.f;
  }
  // stage dstH ONCE (rows 64..127 of hcat): shorts [2048,4096)
  gload_lds16((const char*)(hT + (size_t)n*2048) + wv*1024 + lane*16,
              (char*)SH + 4096 + wv*1024);

  f32x4 aca0 = {0.f,0.f,0.f,0.f}, aca1 = {0.f,0.f,0.f,0.f};  // rot2 accumulators

  for (int k=0; k<deg; ++k){
    const int e = (int)eidTab[n*MAXDEG + k];
    const int src = ei[e];
    // stage srcH (rows 0..63): shorts [0,2048)
    gload_lds16((const char*)(hT + (size_t)src*2048) + wv*1024 + lane*16,
                (char*)SH + wv*1024);
    // stage wigner f32 (coalesced) into wigL
    {
      const float* w = wig + (size_t)e*625;
      for (int idx=tid; idx<625; idx+=256) wigL[idx] = w[idx];
    }
    // rfS -> regs
    s16x4 rvp[2][2];
    {
      const short* rrow = rfS + (size_t)e*640;
#pragma unroll
      for (int t=0;t<2;t++){
        int c0 = (2*wv+t)*16 + q*4;
#pragma unroll
        for (int nt=0;nt<2;nt++){
          int i = nt*16 + lo;
          int l = (i>=16)?4:((i>=9)?3:((i>=4)?2:((i>=1)?1:0)));
          rvp[t][nt] = *(const s16x4*)&rrow[l*128 + c0];
        }
      }
    }
    asm volatile("s_waitcnt vmcnt(0)" ::: "memory");
    __syncthreads();                                 // [#1] srcH + wigL ready

    // build all 4 wigner frags from LDS (before msgs clobbers wigL region)
    bfrag8 wb0, wtb0, wb1 = wz, wtb1 = wz;
#pragma unroll
    for (int m=0;m<8;m++){
      int j = q*8+m;
      wb0[m]  = (j<25) ? f2b(wigL[lo*25+j]) : (short)0;
      wtb0[m] = (j<25) ? f2b(wigL[j*25+lo]) : (short)0;
    }
    if (lo < 9){
#pragma unroll
      for (int m=0;m<8;m++){
        int j = q*8+m;
        wb1[m]  = (j<25) ? f2b(wigL[(16+lo)*25+j]) : (short)0;
        wtb1[m] = (j<25) ? f2b(wigL[j*25+16+lo])   : (short)0;
      }
    }
    // rot1: D[c][i] = sum_j hcat[c][j] * W[i][j]
    f32x4 xacc[2][2];
    {
      const f32x4 zf = {0.f,0.f,0.f,0.f};
#pragma unroll
      for (int t=0;t<2;t++){
        int c = (2*wv+t)*16 + lo;
        bfrag8 a = *(const bfrag8*)&SH[c*32 + ((q ^ ((c>>1)&3))<<3)];
        xacc[t][0] = __builtin_amdgcn_mfma_f32_16x16x32_bf16(a, wb0, zf, 0,0,0);
        xacc[t][1] = __builtin_amdgcn_mfma_f32_16x16x32_bf16(a, wb1, zf, 0,0,0);
      }
    }
    __syncthreads();                                 // [#2] hcat/wigL reads done
    // xeB[i][c] = xe * r
#pragma unroll
    for (int t=0;t<2;t++){
      int c0 = (2*wv+t)*16 + q*4;
#pragma unroll
      for (int nt=0;nt<2;nt++){
        int i = nt*16 + lo;
        s16x4 rv = rvp[t][nt];
        s16x4 o;
#pragma unroll
        for (int r=0;r<4;r++) o[r] = f2b(xacc[t][nt][r]*b2f(rv[r]));
        *(s16x4*)&SH[4096 + i*136 + c0] = o;
      }
    }
    __syncthreads();                                 // [#3] xeB ready

    // extra: alpha heads + gate; dsum += exp(alpha)
    {
      bfrag8 xb[4];
#pragma unroll
      for (int kt=0;kt<4;kt++) xb[kt] = *(const bfrag8*)&SH[4096 + kt*32 + q*8];
      const f32x4 zf = {0.f,0.f,0.f,0.f};
#pragma unroll
      for (int t=0;t<3;t++){
        const int mt = wv*3 + t;     // 12 tiles: 0..7 heads, 8..11 gate
        f32x4 acc = zf;
#pragma unroll
        for (int kt=0;kt<4;kt++){
          bfrag8 a = *(const bfrag8*)&w0eT[(mt*16+lo)*128 + kt*32 + q*8];
          acc = __builtin_amdgcn_mfma_f32_16x16x32_bf16(a, xb[kt], acc, 0,0,0);
        }
        if (mt < 8){
          float s = 0.f;
#pragma unroll
          for (int r=0;r<4;r++) s += silu_f(acc[r]) * adot[mt*16 + q*4 + r];
          s += __shfl_xor(s, 16);
          s += __shfl_xor(s, 32);
          float eh = __expf(s);
          if (lane==0){
            ahead[mt] = eh;
            dsum[mt] += eh;          // single-thread LDS RMW, no race
          }
        } else if (lo==0){
          int g0 = mt*16 - 128 + q*4;
#pragma unroll
          for (int r=0;r<4;r++) gateL[g0+r] = silu_f(acc[r]);
        }
      }
    }
    // msg: msgs[hh][i]
    {
      const int hh = wv*16 + lo;
      const f32x4 zf = {0.f,0.f,0.f,0.f};
      f32x4 acc[2] = {zf,zf};
#pragma unroll
      for (int kt=0;kt<4;kt++){
        bfrag8 b = *(const bfrag8*)&w1t[hh*136 + kt*32 + q*8];
#pragma unroll
        for (int t=0;t<2;t++){
          bfrag8 a = *(const bfrag8*)&SH[4096 + (t*16+lo)*136 + kt*32 + q*8];
          acc[t] = __builtin_amdgcn_mfma_f32_16x16x32_bf16(a, b, acc[t], 0,0,0);
        }
      }
#pragma unroll
      for (int t=0;t<2;t++){
        s16x4 o;
#pragma unroll
        for (int r=0;r<4;r++) o[r] = f2b(acc[t][r]);
        *(s16x4*)&SH[8704 + hh*40 + t*16 + q*4] = o;
      }
    }
    __syncthreads();                                 // [#4] msgs/ahead/gateL ready

    // grid fwd: sg[hh][g]
    {
      const int hh = wv*16 + lo;
      bfrag8 b = *(const bfrag8*)&SH[8704 + hh*40 + q*8];
      const f32x4 zf = {0.f,0.f,0.f,0.f};
      f32x4 acc[3] = {zf,zf,zf};
#pragma unroll
      for (int t=0;t<3;t++){
        bfrag8 a = *(const bfrag8*)&togA[(t*16+lo)*40 + q*8];
        acc[t] = __builtin_amdgcn_mfma_f32_16x16x32_bf16(a, b, acc[t], 0,0,0);
      }
#pragma unroll
      for (int t=0;t<3;t++){
        s16x4 o;
#pragma unroll
        for (int r=0;r<4;r++) o[r] = f2b(silu_f(acc[t][r]));
        *(s16x4*)&SH[4096 + hh*72 + t*16 + q*4] = o;
      }
    }
    // grid bwd: msg2[hh][j] (row0 <- gate), * exp(alpha)
    {
      const int hh = wv*16 + lo;
      const f32x4 zf = {0.f,0.f,0.f,0.f};
      f32x4 acc[2] = {zf,zf};
#pragma unroll
      for (int kt=0;kt<2;kt++){
        bfrag8 b = *(const bfrag8*)&SH[4096 + hh*72 + kt*32 + q*8];
#pragma unroll
        for (int t=0;t<2;t++){
          bfrag8 a = *(const bfrag8*)&fgA[(t*16+lo)*72 + kt*32 + q*8];
          acc[t] = __builtin_amdgcn_mfma_f32_16x16x32_bf16(a, b, acc[t], 0,0,0);
        }
      }
      float ah = ahead[hh>>3];
#pragma unroll
      for (int t=0;t<2;t++){
        s16x4 o;
#pragma unroll
        for (int r=0;r<4;r++){
          int j = t*16 + q*4 + r;
          float v = (j==0) ? gateL[hh] : acc[t][r];
          o[r] = f2b(v*ah);
        }
        *(s16x4*)&SH[8704 + hh*40 + t*16 + q*4] = o;
      }
    }
    // rot2: accumulate into registers across edges (no atomics)
    {
      const int hh = wv*16 + lo;
      bfrag8 b = *(const bfrag8*)&SH[8704 + hh*40 + q*8];
      aca0 = __builtin_amdgcn_mfma_f32_16x16x32_bf16(wtb0, b, aca0, 0,0,0);
      aca1 = __builtin_amdgcn_mfma_f32_16x16x32_bf16(wtb1, b, aca1, 0,0,0);
    }
    __syncthreads();                                 // [#5] msg2/sg dead before next stage
  }

  __syncthreads();   // dsum visible (covers deg==0 too)
  // normalize by softmax denominator and store agg[n]
  {
    const int hh = wv*16 + lo;
    float sc = 1.f/(dsum[hh>>3] + 1e-8f);
    float* aggp = agg + (size_t)n*1600;
#pragma unroll
    for (int r=0;r<4;r++){
      int i0 = q*4 + r;
      aggp[i0*64 + hh] = aca0[r]*sc;
      int i1 = 16 + q*4 + r;
      if (i1 < 25) aggp[i1*64 + hh] = aca1[r]*sc;
    }
  }
}

// ---------------- K4: node update + FFN, MFMA (agg pre-normalized) ----------------
__global__ __launch_bounds__(256,4) void k_node(
  const float* __restrict__ x, const float* __restrict__ aggin,
  const short* __restrict__ projT, const float* __restrict__ gamma2,
  const float* __restrict__ glw, const float* __restrict__ glb,
  const short* __restrict__ fw1T, const float* __restrict__ fb1,
  const short* __restrict__ fw2T, const float* __restrict__ fb2,
  const short* __restrict__ togA, const short* __restrict__ fgA,
  float* __restrict__ out)
{
  __shared__ __align__(16) short P[19072];
  float* xF    = (float*)P;
  short* sgB   = P + 4352;
  short* hh2B  = P + 4352;
  short* f1B   = P + 13568;
  short* aggB  = P + 13568;
  short* xgB   = P + 13568;
  float* invc  = ((float*)P) + 9344;
  float* gateF = ((float*)P) + 9408;
  const int tid = threadIdx.x;
  const int wv = tid>>6, lane = tid&63, lo = lane&15, q = lane>>4;
  const int n = blockIdx.x;
  const s16x4 z4 = {0,0,0,0};

  for (int idx=tid; idx<400; idx+=256){
    int i = idx>>4, k = idx&15;
    const float4 v = *(const float4*)(aggin + (size_t)n*1600 + (size_t)idx*4);
    s16x4 o; o[0]=f2b(v.x); o[1]=f2b(v.y); o[2]=f2b(v.z); o[3]=f2b(v.w);
    *(s16x4*)&aggB[i*72 + k*4] = o;
  }
  for (int idx=tid; idx<126; idx+=256)
    *(s16x4*)&hh2B[25*72 + idx*4] = z4;
  for (int idx=tid; idx<512; idx+=256){
    int f = idx>>2, gg = 48 + (idx&3)*4;
    *(s16x4*)&sgB[f*72 + gg] = z4;
  }
  __syncthreads();

  {
    f32x4 zf={0.f,0.f,0.f,0.f}; f32x4 acc[2]={zf,zf};
    const int c = wv*16 + lo;
#pragma unroll
    for (int kt=0;kt<2;kt++){
      bfrag8 b = *(const bfrag8*)&projT[c*64 + kt*32 + q*8];
#pragma unroll
      for (int t=0;t<2;t++){
        bfrag8 a = *(const bfrag8*)&aggB[(t*16+lo)*72 + kt*32 + q*8];
        acc[t] = __builtin_amdgcn_mfma_f32_16x16x32_bf16(a,b,acc[t],0,0,0);
      }
    }
#pragma unroll
    for (int t=0;t<2;t++)
#pragma unroll
      for (int r=0;r<4;r++){
        int i = t*16 + q*4 + r;
        if (i<25) xF[i*68+c] = acc[t][r] + x[(size_t)n*1600 + i*64 + c];
      }
  }
  __syncthreads();
  if (tid<64){
    float ss=0.f;
#pragma unroll
    for (int i=0;i<25;i++){ float v = xF[i*68+tid]; ss += v*v; }
    invc[tid] = gamma2[tid]*rsqrtf(ss*(1.f/25.f)+1e-6f);
  }
  __syncthreads();
  for (int idx=tid; idx<1600; idx+=256){
    int i=idx>>6, c=idx&63;
    hh2B[i*72+c] = f2b(xF[i*68+c]*invc[c]);
  }
  if (tid<128){
    float a = glb[tid];
#pragma unroll 8
    for (int c=0;c<64;c++) a += xF[c]*invc[c]*glw[c*128+tid];
    gateF[tid] = silu_f(a);
  }
  __syncthreads();

  {
    f32x4 zf={0.f,0.f,0.f,0.f}; f32x4 acc[2][2]={{zf,zf},{zf,zf}};
#pragma unroll
    for (int kt=0;kt<2;kt++){
      bfrag8 a0 = *(const bfrag8*)&hh2B[(lo)*72 + kt*32 + q*8];
      bfrag8 a1 = *(const bfrag8*)&hh2B[(16+lo)*72 + kt*32 + q*8];
#pragma unroll
      for (int s=0;s<2;s++){
        int f = wv*32 + s*16 + lo;
        bfrag8 b = *(const bfrag8*)&fw1T[f*64 + kt*32 + q*8];
        acc[0][s] = __builtin_amdgcn_mfma_f32_16x16x32_bf16(a0,b,acc[0][s],0,0,0);
        acc[1][s] = __builtin_amdgcn_mfma_f32_16x16x32_bf16(a1,b,acc[1][s],0,0,0);
      }
    }
#pragma unroll
    for (int s=0;s<2;s++){
      int f = wv*32 + s*16 + lo;
      float bb = fb1[f];
#pragma unroll
      for (int t=0;t<2;t++){
        s16x4 o;
#pragma unroll
        for (int r=0;r<4;r++){
          int i = t*16+q*4+r;
          o[r] = f2b(acc[t][s][r] + (i==0 ? bb : 0.f));
        }
        *(s16x4*)&f1B[f*40 + t*16 + q*4] = o;
      }
    }
  }
  __syncthreads();

  {
    f32x4 zf={0.f,0.f,0.f,0.f}; f32x4 acc[3][2]={{zf,zf},{zf,zf},{zf,zf}};
    bfrag8 a0 = *(const bfrag8*)&togA[(lo)*40 + q*8];
    bfrag8 a1 = *(const bfrag8*)&togA[(16+lo)*40 + q*8];
    bfrag8 a2 = *(const bfrag8*)&togA[(32+lo)*40 + q*8];
#pragma unroll
    for (int s=0;s<2;s++){
      int f = wv*32 + s*16 + lo;
      bfrag8 b = *(const bfrag8*)&f1B[f*40 + q*8];
      acc[0][s] = __builtin_amdgcn_mfma_f32_16x16x32_bf16(a0,b,acc[0][s],0,0,0);
      acc[1][s] = __builtin_amdgcn_mfma_f32_16x16x32_bf16(a1,b,acc[1][s],0,0,0);
      acc[2][s] = __builtin_amdgcn_mfma_f32_16x16x32_bf16(a2,b,acc[2][s],0,0,0);
    }
#pragma unroll
    for (int s=0;s<2;s++){
      int f = wv*32 + s*16 + lo;
#pragma unroll
      for (int t=0;t<3;t++){
        s16x4 o;
#pragma unroll
        for (int r=0;r<4;r++) o[r] = f2b(silu_f(acc[t][s][r]));
        *(s16x4*)&sgB[f*72 + t*16 + q*4] = o;
      }
    }
  }
  __syncthreads();

  {
    f32x4 zf={0.f,0.f,0.f,0.f}; f32x4 acc[2][2]={{zf,zf},{zf,zf}};
#pragma unroll
    for (int kt=0;kt<2;kt++){
#pragma unroll
      for (int t=0;t<2;t++){
        bfrag8 b = *(const bfrag8*)&fgA[(t*16+lo)*72 + kt*32 + q*8];
#pragma unroll
        for (int s=0;s<2;s++){
          bfrag8 a = *(const bfrag8*)&sgB[(wv*32+s*16+lo)*72 + kt*32 + q*8];
          acc[s][t] = __builtin_amdgcn_mfma_f32_16x16x32_bf16(a,b,acc[s][t],0,0,0);
        }
      }
    }
#pragma unroll
    for (int s=0;s<2;s++){
      int f0 = wv*32 + s*16 + q*4;
#pragma unroll
      for (int t=0;t<2;t++){
        int j = t*16 + lo;
        s16x4 o;
#pragma unroll
        for (int r=0;r<4;r++)
          o[r] = f2b(j==0 ? gateF[f0+r] : acc[s][t][r]);
        *(s16x4*)&xgB[j*136 + f0] = o;
      }
    }
  }
  __syncthreads();

  {
    f32x4 zf={0.f,0.f,0.f,0.f}; f32x4 acc[2]={zf,zf};
    const int c = wv*16 + lo;
#pragma unroll
    for (int kt=0;kt<4;kt++){
      bfrag8 b = *(const bfrag8*)&fw2T[c*128 + kt*32 + q*8];
#pragma unroll
      for (int t=0;t<2;t++){
        bfrag8 a = *(const bfrag8*)&xgB[(t*16+lo)*136 + kt*32 + q*8];
        acc[t] = __builtin_amdgcn_mfma_f32_16x16x32_bf16(a,b,acc[t],0,0,0);
      }
    }
    float bb = fb2[c];
#pragma unroll
    for (int t=0;t<2;t++)
#pragma unroll
      for (int r=0;r<4;r++){
        int i = t*16 + q*4 + r;
        if (i<25)
          out[(size_t)n*1600 + i*64 + c] = xF[i*68+c] + acc[t][r] + (i==0 ? bb : 0.f);
      }
  }
}

extern "C" void kernel_launch(void* const* d_in, const int* in_sizes, int n_in,
                              void* d_out, int out_size, void* d_ws, size_t ws_size,
                              hipStream_t stream) {
  (void)in_sizes; (void)n_in; (void)ws_size; (void)out_size;
  const float* x     = (const float*)d_in[0];
  const int*   ei    = (const int*)d_in[1];
  const int*   an    = (const int*)d_in[2];
  const float* edist = (const float*)d_in[3];
  const float* wig   = (const float*)d_in[4];
  const float* stab  = (const float*)d_in[5];
  const float* ttab  = (const float*)d_in[6];
  const float* rw1   = (const float*)d_in[7];
  const float* rb1   = (const float*)d_in[8];
  const float* rw2   = (const float*)d_in[9];
  const float* rb2   = (const float*)d_in[10];
  const float* rw3   = (const float*)d_in[11];
  const float* rb3   = (const float*)d_in[12];
  const float* W1    = (const float*)d_in[13];
  const float* w0e   = (const float*)d_in[14];
  const float* adot  = (const float*)d_in[15];
  const float* tog   = (const float*)d_in[16];
  const float* fromg = (const float*)d_in[17];
  const float* proj  = (const float*)d_in[18];
  const float* g1    = (const float*)d_in[19];
  const float* g2    = (const float*)d_in[20];
  const float* glw   = (const float*)d_in[21];
  const float* glb   = (const float*)d_in[22];
  const float* fw1   = (const float*)d_in[23];
  const float* fb1   = (const float*)d_in[24];
  const float* fw2   = (const float*)d_in[25];
  const float* fb2   = (const float*)d_in[26];
  float* out = (float*)d_out;

  char* wsb = (char*)d_ws;
  short* hT     = (short*)(wsb);                    // 40,960,000 B
  short* rfS    = (short*)(wsb + 40960000);         // 64,000,000 B
  int*   cnt    = (int*)(wsb + 104960000);          // 40,000 B
  unsigned short* eidTab = (unsigned short*)(wsb + 105000000); // 640,000 B
  short* w1t    = (short*)(wsb + 105640000);        // 17,408
  short* togA   = (short*)(wsb + 105657408);        // 3,840
  short* fgA    = (short*)(wsb + 105661248);        // 4,608
  short* projT  = (short*)(wsb + 105665856);        // 8,192
  short* fw1T   = (short*)(wsb + 105674048);        // 16,384
  short* fw2T   = (short*)(wsb + 105690432);        // 16,384
  short* rw1T   = (short*)(wsb + 105706816);        // 12,288
  short* rw2T   = (short*)(wsb + 105719104);        // 8,192
  short* rw3T   = (short*)(wsb + 105727296);        // 81,920
  short* w0eT   = (short*)(wsb + 105809216);        // 49,152

  hipMemsetAsync(cnt, 0, (size_t)NN*sizeof(int), stream);

  k_wprep<<<32, 256, 0, stream>>>(W1, tog, fromg, proj, fw1, fw2, rw1, rw2, rw3, w0e,
                                  w1t, togA, fgA, projT, fw1T, fw2T,
                                  rw1T, rw2T, rw3T, w0eT);
  k_fill  <<<(NE+255)/256, 256, 0, stream>>>(ei, cnt, eidTab);
  k_rms1  <<<(NN*64+255)/256, 256, 0, stream>>>(x, g1, hT);
  k_radial<<<(NE+31)/32, 256, 0, stream>>>(ei, an, edist, stab, ttab,
                                           rw1T, rb1, rw2T, rb2, rw3T, rb3, rfS);
  k_edge  <<<NN, 256, 0, stream>>>(hT, ei, wig, cnt, eidTab,
                                   w1t, togA, fgA, w0eT, adot, rfS, out);
  k_node  <<<NN, 256, 0, stream>>>(x, out, projT, g2, glw, glb,
                                   fw1T, fb1, fw2T, fb2, togA, fgA, out);
}

// Round 7
// 965.385 us; speedup vs baseline: 1.3255x; 1.3255x over previous
//
#include <hip/hip_runtime.h>
#include <hip/hip_bf16.h>

#define NN 10000
#define NE 50000

typedef __attribute__((ext_vector_type(8))) short bfrag8;  // 8 bf16 = 4 VGPR (MFMA A/B)
typedef __attribute__((ext_vector_type(4))) short s16x4;   // 4 bf16 = b64 store
typedef __attribute__((ext_vector_type(8))) short s16x8;   // 8 bf16 = b128 store
typedef __attribute__((ext_vector_type(4))) float f32x4;   // MFMA C/D

__device__ __forceinline__ float silu_f(float v){ return v / (1.0f + __expf(-v)); }
__device__ __forceinline__ short f2b(float f){           // f32 -> bf16 RNE
  unsigned u = __float_as_uint(f);
  u += 0x7fffu + ((u>>16)&1u);
  return (short)(u>>16);
}
__device__ __forceinline__ float b2f(short s){
  return __uint_as_float(((unsigned)(unsigned short)s)<<16);
}
// async global->LDS: per-lane global addr, wave-uniform LDS base, lane*16 dest
__device__ __forceinline__ void gload_lds16(const void* g, void* l){
  __builtin_amdgcn_global_load_lds(
      (const __attribute__((address_space(1))) void*)g,
      (__attribute__((address_space(3))) void*)l, 16, 0, 0);
}

// ---------------- K0: hT[n][c][j] = bf16(rmsnorm(x)) transposed+swizzled ----------------
__global__ __launch_bounds__(256) void k_rms1(const float* __restrict__ x,
                                              const float* __restrict__ gamma,
                                              short* __restrict__ hT){
  int idx = blockIdx.x*256 + threadIdx.x;
  if (idx >= NN*64) return;
  int n = idx>>6, c = idx&63;
  const float* xp = x + (size_t)n*1600 + c;
  float v[25]; float ss = 0.f;
#pragma unroll
  for (int i=0;i<25;i++){ v[i] = xp[i*64]; ss += v[i]*v[i]; }
  float inv = gamma[c] * rsqrtf(ss*(1.f/25.f) + 1e-6f);
  short* hp = hT + (size_t)n*2048 + c*32;
  const int sw = (c>>1)&3;
#pragma unroll
  for (int s=0;s<4;s++){
    s16x8 o;
#pragma unroll
    for (int k=0;k<8;k++){
      int j = s*8 + k;
      o[k] = (j<25) ? f2b(v[j]*inv) : (short)0;
    }
    *(s16x8*)(hp + ((s ^ sw)<<3)) = o;
  }
}

// ------------- Kprep: weights -> MFMA bf16 layouts -------------
__global__ void k_wprep(const float* __restrict__ W1, const float* __restrict__ tog,
                        const float* __restrict__ fromg, const float* __restrict__ proj,
                        const float* __restrict__ fw1, const float* __restrict__ fw2,
                        const float* __restrict__ rw1, const float* __restrict__ rw2,
                        const float* __restrict__ rw3, const float* __restrict__ w0e,
                        short* __restrict__ w1t, short* __restrict__ togA,
                        short* __restrict__ fgA, short* __restrict__ projT,
                        short* __restrict__ fw1T, short* __restrict__ fw2T,
                        short* __restrict__ rw1T, short* __restrict__ rw2T,
                        short* __restrict__ rw3T, short* __restrict__ w0eT){
  int t0 = blockIdx.x*blockDim.x + threadIdx.x;
  int stride = gridDim.x*blockDim.x;
  for (int idx=t0; idx<64*136; idx+=stride){
    int hh = idx/136, k = idx-136*hh;
    w1t[idx] = (k<128) ? f2b(W1[k*64+hh]) : (short)0;
  }
  for (int idx=t0; idx<48*40; idx+=stride){
    int g = idx/40, i = idx-40*g;
    togA[idx] = (g<36 && i<25) ? f2b(tog[g*25+i]) : (short)0;
  }
  for (int idx=t0; idx<32*72; idx+=stride){
    int j = idx/72, g = idx-72*j;
    fgA[idx] = (j<25 && g<36) ? f2b(fromg[j*36+g]) : (short)0;
  }
  for (int idx=t0; idx<64*64; idx+=stride){   // projT[c][k] = proj[k][c]
    int c = idx>>6, k = idx&63;
    projT[idx] = f2b(proj[k*64+c]);
  }
  for (int idx=t0; idx<128*64; idx+=stride){  // fw1T[f][c] = fw1[c][f]
    int f = idx>>6, c = idx&63;
    fw1T[idx] = f2b(fw1[c*128+f]);
  }
  for (int idx=t0; idx<64*128; idx+=stride){  // fw2T[c][f] = fw2[f][c]
    int c = idx>>7, f = idx&127;
    fw2T[idx] = f2b(fw2[f*64+c]);
  }
  for (int idx=t0; idx<64*96; idx+=stride){   // rw1T[n][k] = rw1[k][n]
    int n = idx/96, k = idx-96*n;
    rw1T[idx] = f2b(rw1[k*64+n]);
  }
  for (int idx=t0; idx<64*64; idx+=stride){   // rw2T[n][k] = rw2[k][n]
    int n = idx>>6, k = idx&63;
    rw2T[idx] = f2b(rw2[k*64+n]);
  }
  for (int idx=t0; idx<640*64; idx+=stride){  // rw3T[n][k] = rw3[k][n]
    int n = idx>>6, k = idx&63;
    rw3T[idx] = f2b(rw3[(size_t)k*640+n]);
  }
  for (int idx=t0; idx<192*128; idx+=stride){ // w0eT[m][c] = w0e[c][m]
    int m = idx>>7, c = idx&127;
    w0eT[idx] = f2b(w0e[c*192+m]);
  }
}

// ---------------- K1: radial MLP, MFMA, 32 edges/block ----------------
__global__ __launch_bounds__(256,4) void k_radial(
  const int* __restrict__ ei, const int* __restrict__ an,
  const float* __restrict__ edist,
  const float* __restrict__ stab, const float* __restrict__ ttab,
  const short* __restrict__ rw1T, const float* __restrict__ rb1,
  const short* __restrict__ rw2T, const float* __restrict__ rb2,
  const short* __restrict__ rw3T, const float* __restrict__ rb3,
  short* __restrict__ rfS)
{
  __shared__ __align__(16) short SP[7936];
  const int tid = threadIdx.x;
  const int wv = tid>>6, lane = tid&63, lo = lane&15, q = lane>>4;
  const int e0 = blockIdx.x*32;
  {
    int e = tid>>3;
    int ee = min(e0+e, NE-1);
    int srcE = ei[ee], dstE = ei[NE+ee];
    const float* dp = edist + (size_t)ee*32;
    const float* sp = stab + (size_t)an[srcE]*32;
    const float* tp = ttab + (size_t)an[dstE]*32;
    int kb = tid&7;
#pragma unroll
    for (int it=0; it<12; ++it){
      int k = kb + it*8;
      float v = (k<32) ? dp[k] : (k<64 ? sp[k-32] : tp[k-64]);
      SP[e*104+k] = f2b(v);
    }
  }
  __syncthreads();
  {
    f32x4 zf={0.f,0.f,0.f,0.f}; f32x4 acc[2]={zf,zf};
#pragma unroll
    for (int kt=0;kt<3;kt++){
      bfrag8 a = *(const bfrag8*)&rw1T[(wv*16+lo)*96 + kt*32 + q*8];
#pragma unroll
      for (int et=0;et<2;et++){
        bfrag8 b = *(const bfrag8*)&SP[(et*16+lo)*104 + kt*32 + q*8];
        acc[et] = __builtin_amdgcn_mfma_f32_16x16x32_bf16(a,b,acc[et],0,0,0);
      }
    }
    int n1 = wv*16 + q*4;
    const float4 bb = *(const float4*)&rb1[n1];
#pragma unroll
    for (int et=0;et<2;et++){
      s16x4 o;
      o[0]=f2b(silu_f(acc[et][0]+bb.x)); o[1]=f2b(silu_f(acc[et][1]+bb.y));
      o[2]=f2b(silu_f(acc[et][2]+bb.z)); o[3]=f2b(silu_f(acc[et][3]+bb.w));
      *(s16x4*)&SP[3328 + (et*16+lo)*72 + n1] = o;
    }
  }
  __syncthreads();
  {
    f32x4 zf={0.f,0.f,0.f,0.f}; f32x4 acc[2]={zf,zf};
#pragma unroll
    for (int kt=0;kt<2;kt++){
      bfrag8 a = *(const bfrag8*)&rw2T[(wv*16+lo)*64 + kt*32 + q*8];
#pragma unroll
      for (int et=0;et<2;et++){
        bfrag8 b = *(const bfrag8*)&SP[3328 + (et*16+lo)*72 + kt*32 + q*8];
        acc[et] = __builtin_amdgcn_mfma_f32_16x16x32_bf16(a,b,acc[et],0,0,0);
      }
    }
    int n2 = wv*16 + q*4;
    const float4 bb = *(const float4*)&rb2[n2];
#pragma unroll
    for (int et=0;et<2;et++){
      s16x4 o;
      o[0]=f2b(silu_f(acc[et][0]+bb.x)); o[1]=f2b(silu_f(acc[et][1]+bb.y));
      o[2]=f2b(silu_f(acc[et][2]+bb.z)); o[3]=f2b(silu_f(acc[et][3]+bb.w));
      *(s16x4*)&SP[5632 + (et*16+lo)*72 + n2] = o;
    }
  }
  __syncthreads();
  {
    bfrag8 bfr[2][2];
#pragma unroll
    for (int et=0;et<2;et++)
#pragma unroll
      for (int kt=0;kt<2;kt++)
        bfr[et][kt] = *(const bfrag8*)&SP[5632 + (et*16+lo)*72 + kt*32 + q*8];
    for (int mi=0; mi<10; ++mi){
      int n3base = (wv + mi*4)*16;
      f32x4 zf={0.f,0.f,0.f,0.f}; f32x4 acc[2]={zf,zf};
#pragma unroll
      for (int kt=0;kt<2;kt++){
        bfrag8 a = *(const bfrag8*)&rw3T[(size_t)(n3base+lo)*64 + kt*32 + q*8];
        acc[0] = __builtin_amdgcn_mfma_f32_16x16x32_bf16(a,bfr[0][kt],acc[0],0,0,0);
        acc[1] = __builtin_amdgcn_mfma_f32_16x16x32_bf16(a,bfr[1][kt],acc[1],0,0,0);
      }
      int n3 = n3base + q*4;
      const float4 bb = *(const float4*)&rb3[n3];
#pragma unroll
      for (int et=0;et<2;et++){
        int e = e0 + et*16 + lo;
        if (e < NE){
          s16x4 o;
          o[0]=f2b(acc[et][0]+bb.x); o[1]=f2b(acc[et][1]+bb.y);
          o[2]=f2b(acc[et][2]+bb.z); o[3]=f2b(acc[et][3]+bb.w);
          *(s16x4*)&rfS[(size_t)e*640 + n3] = o;
        }
      }
    }
  }
}

// ---------------- K3: MFMA edge kernel, edge-parallel, natural order ----------------
// LDS shorts: region A [0,4608): hcatT[128][32]swz -> xeB[32][136] -> sg[64][72]
//             region B [4608,7168): wigL f32[625] (start..barrier#2) -> msgs/msg2[64][40]
//             gateL f32[64] @ [7168,7296); ahead f32[8] @ [7296,7312)
// wigL alias is safe: frags consumed between barrier #1 and #2; msgs written after #3.
__global__ __launch_bounds__(256,8) void k_edge(
  const short* __restrict__ hT, const int* __restrict__ ei,
  const float* __restrict__ wig,
  const short* __restrict__ w1t, const short* __restrict__ togA,
  const short* __restrict__ fgA, const short* __restrict__ w0eT,
  const float* __restrict__ adot,
  const short* __restrict__ rfS, float* __restrict__ asum,
  float* __restrict__ agg)
{
  __shared__ __align__(16) short SH[7312];
  float* wigL  = (float*)&SH[4608];
  float* gateL = (float*)&SH[7168];
  float* ahead = (float*)&SH[7296];
  const int tid = threadIdx.x;
  const int wv = tid>>6, lane = tid&63, lo = lane&15, q = lane>>4;
  const int e = blockIdx.x;
  const int src = ei[e], dst = ei[NE+e];

  // stage hcatT[128][32] (src rows 0..63, dst rows 64..127) via global_load_lds
  {
    const char* g0 = (const char*)(hT + (size_t)src*2048) + wv*1024 + lane*16;
    const char* g1 = (const char*)(hT + (size_t)dst*2048) + wv*1024 + lane*16;
    gload_lds16(g0, (char*)SH + wv*1024);
    gload_lds16(g1, (char*)SH + 4096 + wv*1024);
  }
  // zero region-A tail not covered by staging (kills uninit-LDS NaN reads)
  {
    const s16x4 z4 = {0,0,0,0};
    if (tid < 128) *(s16x4*)&SH[4096 + tid*4] = z4;
  }
  // stage wigner f32 coalesced into wigL (region B; dead until msg phase)
  {
    const float* w = wig + (size_t)e*625;
    for (int idx=tid; idx<625; idx+=256) wigL[idx] = w[idx];
  }
  // rfS -> regs
  s16x4 rvp[2][2];
  {
    const short* rrow = rfS + (size_t)e*640;
#pragma unroll
    for (int t=0;t<2;t++){
      int c0 = (2*wv+t)*16 + q*4;
#pragma unroll
      for (int nt=0;nt<2;nt++){
        int i = nt*16 + lo;
        int l = (i>=16)?4:((i>=9)?3:((i>=4)?2:((i>=1)?1:0)));
        rvp[t][nt] = *(const s16x4*)&rrow[l*128 + c0];
      }
    }
  }
  asm volatile("s_waitcnt vmcnt(0)" ::: "memory");
  __syncthreads();                                   // [#1] hcatT + wigL ready

  // build all 4 wigner frags from LDS (conflict-free: stride 25 dwords, 25 coprime 32)
  const bfrag8 wz = {0,0,0,0,0,0,0,0};
  bfrag8 wb0, wtb0, wb1 = wz, wtb1 = wz;
#pragma unroll
  for (int m=0;m<8;m++){
    int j = q*8+m;
    wb0[m]  = (j<25) ? f2b(wigL[lo*25+j]) : (short)0;
    wtb0[m] = (j<25) ? f2b(wigL[j*25+lo]) : (short)0;
  }
  if (lo < 9){
#pragma unroll
    for (int m=0;m<8;m++){
      int j = q*8+m;
      wb1[m]  = (j<25) ? f2b(wigL[(16+lo)*25+j]) : (short)0;
      wtb1[m] = (j<25) ? f2b(wigL[j*25+16+lo])   : (short)0;
    }
  }

  // rot1 MFMA: D[c][i] = sum_j hcatT[c][j] * W[i][j]
  f32x4 xacc[2][2];
  {
    const f32x4 zf = {0.f,0.f,0.f,0.f};
#pragma unroll
    for (int t=0;t<2;t++){
      int c = (2*wv+t)*16 + lo;
      bfrag8 a = *(const bfrag8*)&SH[c*32 + ((q ^ ((c>>1)&3))<<3)];
      xacc[t][0] = __builtin_amdgcn_mfma_f32_16x16x32_bf16(a, wb0, zf, 0,0,0);
      xacc[t][1] = __builtin_amdgcn_mfma_f32_16x16x32_bf16(a, wb1, zf, 0,0,0);
    }
  }
  __syncthreads();                                   // [#2] hcatT + wigL dead
  // epilogue: xeB[i][c] = xe * r
#pragma unroll
  for (int t=0;t<2;t++){
    int c0 = (2*wv+t)*16 + q*4;
#pragma unroll
    for (int nt=0;nt<2;nt++){
      int i = nt*16 + lo;
      s16x4 rv = rvp[t][nt];
      s16x4 o;
#pragma unroll
      for (int r=0;r<4;r++) o[r] = f2b(xacc[t][nt][r]*b2f(rv[r]));
      *(s16x4*)&SH[i*136 + c0] = o;
    }
  }
  __syncthreads();                                   // [#3] xeB ready

  // extra: D = w0eT(192x128) @ broadcast(xe row0) -> alpha heads + gate
  {
    bfrag8 xb[4];
#pragma unroll
    for (int kt=0;kt<4;kt++) xb[kt] = *(const bfrag8*)&SH[kt*32 + q*8];  // row 0, bcast
    const f32x4 zf = {0.f,0.f,0.f,0.f};
#pragma unroll
    for (int t=0;t<3;t++){
      const int mt = wv*3 + t;     // 12 tiles: 0..7 heads, 8..11 gate
      f32x4 acc = zf;
#pragma unroll
      for (int kt=0;kt<4;kt++){
        bfrag8 a = *(const bfrag8*)&w0eT[(mt*16+lo)*128 + kt*32 + q*8];
        acc = __builtin_amdgcn_mfma_f32_16x16x32_bf16(a, xb[kt], acc, 0,0,0);
      }
      if (mt < 8){
        float s = 0.f;
#pragma unroll
        for (int r=0;r<4;r++) s += silu_f(acc[r]) * adot[mt*16 + q*4 + r];
        s += __shfl_xor(s, 16);
        s += __shfl_xor(s, 32);
        float eh = __expf(s);
        if (lane==0){
          ahead[mt] = eh;
          unsafeAtomicAdd(&asum[(size_t)dst*8 + mt], eh);
        }
      } else if (lo==0){
        int g0 = mt*16 - 128 + q*4;
#pragma unroll
        for (int r=0;r<4;r++) gateL[g0+r] = silu_f(acc[r]);
      }
    }
  }
  // msg: msgs[hh][i] (wave-local rows; overwrites wigL region — past barrier #3)
  {
    const int hh = wv*16 + lo;
    const f32x4 zf = {0.f,0.f,0.f,0.f};
    f32x4 acc[2] = {zf,zf};
#pragma unroll
    for (int kt=0;kt<4;kt++){
      bfrag8 b = *(const bfrag8*)&w1t[hh*136 + kt*32 + q*8];
#pragma unroll
      for (int t=0;t<2;t++){
        bfrag8 a = *(const bfrag8*)&SH[(t*16+lo)*136 + kt*32 + q*8];
        acc[t] = __builtin_amdgcn_mfma_f32_16x16x32_bf16(a, b, acc[t], 0,0,0);
      }
    }
#pragma unroll
    for (int t=0;t<2;t++){
      s16x4 o;
#pragma unroll
      for (int r=0;r<4;r++) o[r] = f2b(acc[t][r]);
      *(s16x4*)&SH[4608 + hh*40 + t*16 + q*4] = o;
    }
  }
  __syncthreads();                 // [#4] xeB dead (sg aliases it); ahead/gateL visible

  // grid fwd: sg[hh][g] @ region A
  {
    const int hh = wv*16 + lo;
    bfrag8 b = *(const bfrag8*)&SH[4608 + hh*40 + q*8];
    const f32x4 zf = {0.f,0.f,0.f,0.f};
    f32x4 acc[3] = {zf,zf,zf};
#pragma unroll
    for (int t=0;t<3;t++){
      bfrag8 a = *(const bfrag8*)&togA[(t*16+lo)*40 + q*8];
      acc[t] = __builtin_amdgcn_mfma_f32_16x16x32_bf16(a, b, acc[t], 0,0,0);
    }
#pragma unroll
    for (int t=0;t<3;t++){
      s16x4 o;
#pragma unroll
      for (int r=0;r<4;r++) o[r] = f2b(silu_f(acc[t][r]));
      *(s16x4*)&SH[hh*72 + t*16 + q*4] = o;
    }
  }
  // grid bwd: msg2[hh][j] (row0 <- gate), * exp(alpha)
  {
    const int hh = wv*16 + lo;
    const f32x4 zf = {0.f,0.f,0.f,0.f};
    f32x4 acc[2] = {zf,zf};
#pragma unroll
    for (int kt=0;kt<2;kt++){
      bfrag8 b = *(const bfrag8*)&SH[hh*72 + kt*32 + q*8];
#pragma unroll
      for (int t=0;t<2;t++){
        bfrag8 a = *(const bfrag8*)&fgA[(t*16+lo)*72 + kt*32 + q*8];
        acc[t] = __builtin_amdgcn_mfma_f32_16x16x32_bf16(a, b, acc[t], 0,0,0);
      }
    }
    float ah = ahead[hh>>3];
#pragma unroll
    for (int t=0;t<2;t++){
      s16x4 o;
#pragma unroll
      for (int r=0;r<4;r++){
        int j = t*16 + q*4 + r;
        float v = (j==0) ? gateL[hh] : acc[t][r];
        o[r] = f2b(v*ah);
      }
      *(s16x4*)&SH[4608 + hh*40 + t*16 + q*4] = o;
    }
  }
  // rot2 + atomic scatter (wT frags in VGPRs; random dst order decorrelates targets)
  {
    const int hh = wv*16 + lo;
    bfrag8 b = *(const bfrag8*)&SH[4608 + hh*40 + q*8];
    const f32x4 zf = {0.f,0.f,0.f,0.f};
    f32x4 acc0 = __builtin_amdgcn_mfma_f32_16x16x32_bf16(wtb0, b, zf, 0,0,0);
    f32x4 acc1 = __builtin_amdgcn_mfma_f32_16x16x32_bf16(wtb1, b, zf, 0,0,0);
    float* aggp = agg + (size_t)dst*1600;
#pragma unroll
    for (int r=0;r<4;r++){
      int i0 = q*4 + r;                       // 0..15 < 25 always
      unsafeAtomicAdd(&aggp[i0*64 + hh], acc0[r]);
      int i1 = 16 + q*4 + r;
      if (i1 < 25) unsafeAtomicAdd(&aggp[i1*64 + hh], acc1[r]);
    }
  }
}

// ---------------- K4: node update + FFN, MFMA ----------------
__global__ __launch_bounds__(256,4) void k_node(
  const float* __restrict__ x, const float* __restrict__ aggin,
  const float* __restrict__ asum,
  const short* __restrict__ projT, const float* __restrict__ gamma2,
  const float* __restrict__ glw, const float* __restrict__ glb,
  const short* __restrict__ fw1T, const float* __restrict__ fb1,
  const short* __restrict__ fw2T, const float* __restrict__ fb2,
  const short* __restrict__ togA, const short* __restrict__ fgA,
  float* __restrict__ out)
{
  __shared__ __align__(16) short P[19072];
  float* xF    = (float*)P;
  short* sgB   = P + 4352;
  short* hh2B  = P + 4352;
  short* f1B   = P + 13568;
  short* aggB  = P + 13568;
  short* xgB   = P + 13568;
  float* invc  = ((float*)P) + 9344;
  float* gateF = ((float*)P) + 9408;
  const int tid = threadIdx.x;
  const int wv = tid>>6, lane = tid&63, lo = lane&15, q = lane>>4;
  const int n = blockIdx.x;
  const s16x4 z4 = {0,0,0,0};

  for (int idx=tid; idx<400; idx+=256){
    int i = idx>>4, k = idx&15;
    float sc = 1.f/(asum[(size_t)n*8 + (k>>1)] + 1e-8f);
    const float4 v = *(const float4*)(aggin + (size_t)n*1600 + (size_t)idx*4);
    s16x4 o; o[0]=f2b(v.x*sc); o[1]=f2b(v.y*sc); o[2]=f2b(v.z*sc); o[3]=f2b(v.w*sc);
    *(s16x4*)&aggB[i*72 + k*4] = o;
  }
  for (int idx=tid; idx<126; idx+=256)
    *(s16x4*)&hh2B[25*72 + idx*4] = z4;
  for (int idx=tid; idx<512; idx+=256){
    int f = idx>>2, gg = 48 + (idx&3)*4;
    *(s16x4*)&sgB[f*72 + gg] = z4;
  }
  __syncthreads();

  {
    f32x4 zf={0.f,0.f,0.f,0.f}; f32x4 acc[2]={zf,zf};
    const int c = wv*16 + lo;
#pragma unroll
    for (int kt=0;kt<2;kt++){
      bfrag8 b = *(const bfrag8*)&projT[c*64 + kt*32 + q*8];
#pragma unroll
      for (int t=0;t<2;t++){
        bfrag8 a = *(const bfrag8*)&aggB[(t*16+lo)*72 + kt*32 + q*8];
        acc[t] = __builtin_amdgcn_mfma_f32_16x16x32_bf16(a,b,acc[t],0,0,0);
      }
    }
#pragma unroll
    for (int t=0;t<2;t++)
#pragma unroll
      for (int r=0;r<4;r++){
        int i = t*16 + q*4 + r;
        if (i<25) xF[i*68+c] = acc[t][r] + x[(size_t)n*1600 + i*64 + c];
      }
  }
  __syncthreads();
  if (tid<64){
    float ss=0.f;
#pragma unroll
    for (int i=0;i<25;i++){ float v = xF[i*68+tid]; ss += v*v; }
    invc[tid] = gamma2[tid]*rsqrtf(ss*(1.f/25.f)+1e-6f);
  }
  __syncthreads();
  for (int idx=tid; idx<1600; idx+=256){
    int i=idx>>6, c=idx&63;
    hh2B[i*72+c] = f2b(xF[i*68+c]*invc[c]);
  }
  if (tid<128){
    float a = glb[tid];
#pragma unroll 8
    for (int c=0;c<64;c++) a += xF[c]*invc[c]*glw[c*128+tid];
    gateF[tid] = silu_f(a);
  }
  __syncthreads();

  {
    f32x4 zf={0.f,0.f,0.f,0.f}; f32x4 acc[2][2]={{zf,zf},{zf,zf}};
#pragma unroll
    for (int kt=0;kt<2;kt++){
      bfrag8 a0 = *(const bfrag8*)&hh2B[(lo)*72 + kt*32 + q*8];
      bfrag8 a1 = *(const bfrag8*)&hh2B[(16+lo)*72 + kt*32 + q*8];
#pragma unroll
      for (int s=0;s<2;s++){
        int f = wv*32 + s*16 + lo;
        bfrag8 b = *(const bfrag8*)&fw1T[f*64 + kt*32 + q*8];
        acc[0][s] = __builtin_amdgcn_mfma_f32_16x16x32_bf16(a0,b,acc[0][s],0,0,0);
        acc[1][s] = __builtin_amdgcn_mfma_f32_16x16x32_bf16(a1,b,acc[1][s],0,0,0);
      }
    }
#pragma unroll
    for (int s=0;s<2;s++){
      int f = wv*32 + s*16 + lo;
      float bb = fb1[f];
#pragma unroll
      for (int t=0;t<2;t++){
        s16x4 o;
#pragma unroll
        for (int r=0;r<4;r++){
          int i = t*16+q*4+r;
          o[r] = f2b(acc[t][s][r] + (i==0 ? bb : 0.f));
        }
        *(s16x4*)&f1B[f*40 + t*16 + q*4] = o;
      }
    }
  }
  __syncthreads();

  {
    f32x4 zf={0.f,0.f,0.f,0.f}; f32x4 acc[3][2]={{zf,zf},{zf,zf},{zf,zf}};
    bfrag8 a0 = *(const bfrag8*)&togA[(lo)*40 + q*8];
    bfrag8 a1 = *(const bfrag8*)&togA[(16+lo)*40 + q*8];
    bfrag8 a2 = *(const bfrag8*)&togA[(32+lo)*40 + q*8];
#pragma unroll
    for (int s=0;s<2;s++){
      int f = wv*32 + s*16 + lo;
      bfrag8 b = *(const bfrag8*)&f1B[f*40 + q*8];
      acc[0][s] = __builtin_amdgcn_mfma_f32_16x16x32_bf16(a0,b,acc[0][s],0,0,0);
      acc[1][s] = __builtin_amdgcn_mfma_f32_16x16x32_bf16(a1,b,acc[1][s],0,0,0);
      acc[2][s] = __builtin_amdgcn_mfma_f32_16x16x32_bf16(a2,b,acc[2][s],0,0,0);
    }
#pragma unroll
    for (int s=0;s<2;s++){
      int f = wv*32 + s*16 + lo;
#pragma unroll
      for (int t=0;t<3;t++){
        s16x4 o;
#pragma unroll
        for (int r=0;r<4;r++) o[r] = f2b(silu_f(acc[t][s][r]));
        *(s16x4*)&sgB[f*72 + t*16 + q*4] = o;
      }
    }
  }
  __syncthreads();

  {
    f32x4 zf={0.f,0.f,0.f,0.f}; f32x4 acc[2][2]={{zf,zf},{zf,zf}};
#pragma unroll
    for (int kt=0;kt<2;kt++){
#pragma unroll
      for (int t=0;t<2;t++){
        bfrag8 b = *(const bfrag8*)&fgA[(t*16+lo)*72 + kt*32 + q*8];
#pragma unroll
        for (int s=0;s<2;s++){
          bfrag8 a = *(const bfrag8*)&sgB[(wv*32+s*16+lo)*72 + kt*32 + q*8];
          acc[s][t] = __builtin_amdgcn_mfma_f32_16x16x32_bf16(a,b,acc[s][t],0,0,0);
        }
      }
    }
#pragma unroll
    for (int s=0;s<2;s++){
      int f0 = wv*32 + s*16 + q*4;
#pragma unroll
      for (int t=0;t<2;t++){
        int j = t*16 + lo;
        s16x4 o;
#pragma unroll
        for (int r=0;r<4;r++)
          o[r] = f2b(j==0 ? gateF[f0+r] : acc[s][t][r]);
        *(s16x4*)&xgB[j*136 + f0] = o;
      }
    }
  }
  __syncthreads();

  {
    f32x4 zf={0.f,0.f,0.f,0.f}; f32x4 acc[2]={zf,zf};
    const int c = wv*16 + lo;
#pragma unroll
    for (int kt=0;kt<4;kt++){
      bfrag8 b = *(const bfrag8*)&fw2T[c*128 + kt*32 + q*8];
#pragma unroll
      for (int t=0;t<2;t++){
        bfrag8 a = *(const bfrag8*)&xgB[(t*16+lo)*136 + kt*32 + q*8];
        acc[t] = __builtin_amdgcn_mfma_f32_16x16x32_bf16(a,b,acc[t],0,0,0);
      }
    }
    float bb = fb2[c];
#pragma unroll
    for (int t=0;t<2;t++)
#pragma unroll
      for (int r=0;r<4;r++){
        int i = t*16 + q*4 + r;
        if (i<25)
          out[(size_t)n*1600 + i*64 + c] = xF[i*68+c] + acc[t][r] + (i==0 ? bb : 0.f);
      }
  }
}

extern "C" void kernel_launch(void* const* d_in, const int* in_sizes, int n_in,
                              void* d_out, int out_size, void* d_ws, size_t ws_size,
                              hipStream_t stream) {
  (void)in_sizes; (void)n_in; (void)ws_size;
  const float* x     = (const float*)d_in[0];
  const int*   ei    = (const int*)d_in[1];
  const int*   an    = (const int*)d_in[2];
  const float* edist = (const float*)d_in[3];
  const float* wig   = (const float*)d_in[4];
  const float* stab  = (const float*)d_in[5];
  const float* ttab  = (const float*)d_in[6];
  const float* rw1   = (const float*)d_in[7];
  const float* rb1   = (const float*)d_in[8];
  const float* rw2   = (const float*)d_in[9];
  const float* rb2   = (const float*)d_in[10];
  const float* rw3   = (const float*)d_in[11];
  const float* rb3   = (const float*)d_in[12];
  const float* W1    = (const float*)d_in[13];
  const float* w0e   = (const float*)d_in[14];
  const float* adot  = (const float*)d_in[15];
  const float* tog   = (const float*)d_in[16];
  const float* fromg = (const float*)d_in[17];
  const float* proj  = (const float*)d_in[18];
  const float* g1    = (const float*)d_in[19];
  const float* g2    = (const float*)d_in[20];
  const float* glw   = (const float*)d_in[21];
  const float* glb   = (const float*)d_in[22];
  const float* fw1   = (const float*)d_in[23];
  const float* fb1   = (const float*)d_in[24];
  const float* fw2   = (const float*)d_in[25];
  const float* fb2   = (const float*)d_in[26];
  float* out = (float*)d_out;

  char* wsb = (char*)d_ws;
  short* hT     = (short*)(wsb);                    // 40,960,000 B
  short* rfS    = (short*)(wsb + 40960000);         // 64,000,000 B
  float* asum   = (float*)(wsb + 104960000);        // 320,000 B
  short* w1t    = (short*)(wsb + 105280000);        // 17,408
  short* togA   = (short*)(wsb + 105297408);        // 3,840
  short* fgA    = (short*)(wsb + 105301248);        // 4,608
  short* projT  = (short*)(wsb + 105305856);        // 8,192
  short* fw1T   = (short*)(wsb + 105314048);        // 16,384
  short* fw2T   = (short*)(wsb + 105330432);        // 16,384
  short* rw1T   = (short*)(wsb + 105346816);        // 12,288
  short* rw2T   = (short*)(wsb + 105359104);        // 8,192
  short* rw3T   = (short*)(wsb + 105367296);        // 81,920
  short* w0eT   = (short*)(wsb + 105449216);        // 49,152

  hipMemsetAsync(asum, 0, (size_t)NN*8*sizeof(float), stream);
  hipMemsetAsync(d_out, 0, (size_t)out_size*sizeof(float), stream);  // d_out = agg

  k_wprep<<<32, 256, 0, stream>>>(W1, tog, fromg, proj, fw1, fw2, rw1, rw2, rw3, w0e,
                                  w1t, togA, fgA, projT, fw1T, fw2T,
                                  rw1T, rw2T, rw3T, w0eT);
  k_rms1  <<<(NN*64+255)/256, 256, 0, stream>>>(x, g1, hT);
  k_radial<<<(NE+31)/32, 256, 0, stream>>>(ei, an, edist, stab, ttab,
                                           rw1T, rb1, rw2T, rb2, rw3T, rb3, rfS);
  k_edge  <<<NE, 256, 0, stream>>>(hT, ei, wig, w1t, togA, fgA, w0eT, adot,
                                   rfS, asum, out);
  k_node  <<<NN, 256, 0, stream>>>(x, out, asum, projT, g2, glw, glb,
                                   fw1T, fb1, fw2T, fb2, togA, fgA, out);
}

// Round 9
// 961.484 us; speedup vs baseline: 1.3308x; 1.0041x over previous
//
#include <hip/hip_runtime.h>
#include <hip/hip_bf16.h>

#define NN 10000
#define NE 50000

typedef __attribute__((ext_vector_type(8))) short bfrag8;  // 8 bf16 = 4 VGPR (MFMA A/B)
typedef __attribute__((ext_vector_type(4))) short s16x4;   // 4 bf16 = b64 store
typedef __attribute__((ext_vector_type(8))) short s16x8;   // 8 bf16 = b128 store
typedef __attribute__((ext_vector_type(4))) float f32x4;   // MFMA C/D

__device__ __forceinline__ float silu_f(float v){ return v / (1.0f + __expf(-v)); }
__device__ __forceinline__ short f2b(float f){           // f32 -> bf16 RNE (prep only)
  unsigned u = __float_as_uint(f);
  u += 0x7fffu + ((u>>16)&1u);
  return (short)(u>>16);
}
__device__ __forceinline__ float b2f(short s){
  return __uint_as_float(((unsigned)(unsigned short)s)<<16);
}
// packed f32x2 -> bf16x2 (RNE) via HIP intrinsic (compiler lowers to native cvt)
__device__ __forceinline__ unsigned cvtpk(float a, float b){
  union { __hip_bfloat162 h2; unsigned u; } x;
  x.h2 = __float22bfloat162_rn(make_float2(a,b));   // .x -> low 16, .y -> high 16
  return x.u;
}
__device__ __forceinline__ s16x4 pk4(float a, float b, float c, float d){
  union { unsigned u[2]; s16x4 s; } x;
  x.u[0] = cvtpk(a,b); x.u[1] = cvtpk(c,d);
  return x.s;
}
// async global->LDS: per-lane global addr, wave-uniform LDS base, lane*16 dest
__device__ __forceinline__ void gload_lds16(const void* g, void* l){
  __builtin_amdgcn_global_load_lds(
      (const __attribute__((address_space(1))) void*)g,
      (__attribute__((address_space(3))) void*)l, 16, 0, 0);
}

// ---------------- K0: hT[n][c][j] = bf16(rmsnorm(x)) transposed+swizzled ----------------
__global__ __launch_bounds__(256) void k_rms1(const float* __restrict__ x,
                                              const float* __restrict__ gamma,
                                              short* __restrict__ hT){
  int idx = blockIdx.x*256 + threadIdx.x;
  if (idx >= NN*64) return;
  int n = idx>>6, c = idx&63;
  const float* xp = x + (size_t)n*1600 + c;
  float v[25]; float ss = 0.f;
#pragma unroll
  for (int i=0;i<25;i++){ v[i] = xp[i*64]; ss += v[i]*v[i]; }
  float inv = gamma[c] * rsqrtf(ss*(1.f/25.f) + 1e-6f);
  short* hp = hT + (size_t)n*2048 + c*32;
  const int sw = (c>>1)&3;
#pragma unroll
  for (int s=0;s<4;s++){
    union { unsigned u[4]; s16x8 s8; } o;
#pragma unroll
    for (int k=0;k<4;k++){
      int j0 = s*8 + 2*k, j1 = j0+1;
      float a = (j0<25) ? v[j0]*inv : 0.f;
      float b = (j1<25) ? v[j1]*inv : 0.f;
      o.u[k] = cvtpk(a,b);
    }
    *(s16x8*)(hp + ((s ^ sw)<<3)) = o.s8;
  }
}

// ------------- Kprep: weights -> MFMA bf16 layouts -------------
__global__ void k_wprep(const float* __restrict__ W1, const float* __restrict__ tog,
                        const float* __restrict__ fromg, const float* __restrict__ proj,
                        const float* __restrict__ fw1, const float* __restrict__ fw2,
                        const float* __restrict__ rw1, const float* __restrict__ rw2,
                        const float* __restrict__ rw3, const float* __restrict__ w0e,
                        short* __restrict__ w1t, short* __restrict__ togA,
                        short* __restrict__ fgA, short* __restrict__ projT,
                        short* __restrict__ fw1T, short* __restrict__ fw2T,
                        short* __restrict__ rw1T, short* __restrict__ rw2T,
                        short* __restrict__ rw3T, short* __restrict__ w0eT){
  int t0 = blockIdx.x*blockDim.x + threadIdx.x;
  int stride = gridDim.x*blockDim.x;
  for (int idx=t0; idx<64*136; idx+=stride){
    int hh = idx/136, k = idx-136*hh;
    w1t[idx] = (k<128) ? f2b(W1[k*64+hh]) : (short)0;
  }
  for (int idx=t0; idx<48*40; idx+=stride){
    int g = idx/40, i = idx-40*g;
    togA[idx] = (g<36 && i<25) ? f2b(tog[g*25+i]) : (short)0;
  }
  for (int idx=t0; idx<32*72; idx+=stride){
    int j = idx/72, g = idx-72*j;
    fgA[idx] = (j<25 && g<36) ? f2b(fromg[j*36+g]) : (short)0;
  }
  for (int idx=t0; idx<64*64; idx+=stride){   // projT[c][k] = proj[k][c]
    int c = idx>>6, k = idx&63;
    projT[idx] = f2b(proj[k*64+c]);
  }
  for (int idx=t0; idx<128*64; idx+=stride){  // fw1T[f][c] = fw1[c][f]
    int f = idx>>6, c = idx&63;
    fw1T[idx] = f2b(fw1[c*128+f]);
  }
  for (int idx=t0; idx<64*128; idx+=stride){  // fw2T[c][f] = fw2[f][c]
    int c = idx>>7, f = idx&127;
    fw2T[idx] = f2b(fw2[f*64+c]);
  }
  for (int idx=t0; idx<64*96; idx+=stride){   // rw1T[n][k] = rw1[k][n]
    int n = idx/96, k = idx-96*n;
    rw1T[idx] = f2b(rw1[k*64+n]);
  }
  for (int idx=t0; idx<64*64; idx+=stride){   // rw2T[n][k] = rw2[k][n]
    int n = idx>>6, k = idx&63;
    rw2T[idx] = f2b(rw2[k*64+n]);
  }
  for (int idx=t0; idx<640*64; idx+=stride){  // rw3T[n][k] = rw3[k][n]
    int n = idx>>6, k = idx&63;
    rw3T[idx] = f2b(rw3[(size_t)k*640+n]);
  }
  for (int idx=t0; idx<192*128; idx+=stride){ // w0eT[m][c] = w0e[c][m]
    int m = idx>>7, c = idx&127;
    w0eT[idx] = f2b(w0e[c*192+m]);
  }
}

// ---------------- K1: radial MLP, MFMA, 32 edges/block ----------------
__global__ __launch_bounds__(256,4) void k_radial(
  const int* __restrict__ ei, const int* __restrict__ an,
  const float* __restrict__ edist,
  const float* __restrict__ stab, const float* __restrict__ ttab,
  const short* __restrict__ rw1T, const float* __restrict__ rb1,
  const short* __restrict__ rw2T, const float* __restrict__ rb2,
  const short* __restrict__ rw3T, const float* __restrict__ rb3,
  short* __restrict__ rfS)
{
  __shared__ __align__(16) short SP[7936];
  const int tid = threadIdx.x;
  const int wv = tid>>6, lane = tid&63, lo = lane&15, q = lane>>4;
  const int e0 = blockIdx.x*32;
  {
    int e = tid>>3;
    int ee = min(e0+e, NE-1);
    int srcE = ei[ee], dstE = ei[NE+ee];
    const float* dp = edist + (size_t)ee*32;
    const float* sp = stab + (size_t)an[srcE]*32;
    const float* tp = ttab + (size_t)an[dstE]*32;
    int kb = tid&7;
#pragma unroll
    for (int it=0; it<12; ++it){
      int k = kb + it*8;
      float v = (k<32) ? dp[k] : (k<64 ? sp[k-32] : tp[k-64]);
      SP[e*104+k] = f2b(v);
    }
  }
  __syncthreads();
  {
    f32x4 zf={0.f,0.f,0.f,0.f}; f32x4 acc[2]={zf,zf};
#pragma unroll
    for (int kt=0;kt<3;kt++){
      bfrag8 a = *(const bfrag8*)&rw1T[(wv*16+lo)*96 + kt*32 + q*8];
#pragma unroll
      for (int et=0;et<2;et++){
        bfrag8 b = *(const bfrag8*)&SP[(et*16+lo)*104 + kt*32 + q*8];
        acc[et] = __builtin_amdgcn_mfma_f32_16x16x32_bf16(a,b,acc[et],0,0,0);
      }
    }
    int n1 = wv*16 + q*4;
    const float4 bb = *(const float4*)&rb1[n1];
#pragma unroll
    for (int et=0;et<2;et++){
      *(s16x4*)&SP[3328 + (et*16+lo)*72 + n1] =
        pk4(silu_f(acc[et][0]+bb.x), silu_f(acc[et][1]+bb.y),
            silu_f(acc[et][2]+bb.z), silu_f(acc[et][3]+bb.w));
    }
  }
  __syncthreads();
  {
    f32x4 zf={0.f,0.f,0.f,0.f}; f32x4 acc[2]={zf,zf};
#pragma unroll
    for (int kt=0;kt<2;kt++){
      bfrag8 a = *(const bfrag8*)&rw2T[(wv*16+lo)*64 + kt*32 + q*8];
#pragma unroll
      for (int et=0;et<2;et++){
        bfrag8 b = *(const bfrag8*)&SP[3328 + (et*16+lo)*72 + kt*32 + q*8];
        acc[et] = __builtin_amdgcn_mfma_f32_16x16x32_bf16(a,b,acc[et],0,0,0);
      }
    }
    int n2 = wv*16 + q*4;
    const float4 bb = *(const float4*)&rb2[n2];
#pragma unroll
    for (int et=0;et<2;et++){
      *(s16x4*)&SP[5632 + (et*16+lo)*72 + n2] =
        pk4(silu_f(acc[et][0]+bb.x), silu_f(acc[et][1]+bb.y),
            silu_f(acc[et][2]+bb.z), silu_f(acc[et][3]+bb.w));
    }
  }
  __syncthreads();
  {
    bfrag8 bfr[2][2];
#pragma unroll
    for (int et=0;et<2;et++)
#pragma unroll
      for (int kt=0;kt<2;kt++)
        bfr[et][kt] = *(const bfrag8*)&SP[5632 + (et*16+lo)*72 + kt*32 + q*8];
    for (int mi=0; mi<10; ++mi){
      int n3base = (wv + mi*4)*16;
      f32x4 zf={0.f,0.f,0.f,0.f}; f32x4 acc[2]={zf,zf};
#pragma unroll
      for (int kt=0;kt<2;kt++){
        bfrag8 a = *(const bfrag8*)&rw3T[(size_t)(n3base+lo)*64 + kt*32 + q*8];
        acc[0] = __builtin_amdgcn_mfma_f32_16x16x32_bf16(a,bfr[0][kt],acc[0],0,0,0);
        acc[1] = __builtin_amdgcn_mfma_f32_16x16x32_bf16(a,bfr[1][kt],acc[1],0,0,0);
      }
      int n3 = n3base + q*4;
      const float4 bb = *(const float4*)&rb3[n3];
#pragma unroll
      for (int et=0;et<2;et++){
        int e = e0 + et*16 + lo;
        if (e < NE){
          *(s16x4*)&rfS[(size_t)e*640 + n3] =
            pk4(acc[et][0]+bb.x, acc[et][1]+bb.y, acc[et][2]+bb.z, acc[et][3]+bb.w);
        }
      }
    }
  }
}

// ---------------- K3: MFMA edge kernel, edge-parallel, natural order ----------------
// LDS shorts: region A [0,4608): hcatT[128][32]swz -> xeB[32][136] -> sg[64][72]
//             region B [4608,7168): wigL f32[625] (start..barrier#2) -> msgs/msg2[64][40]
//             gateL f32[64] @ [7168,7296); ahead f32[8] @ [7296,7312)
__global__ __launch_bounds__(256,8) void k_edge(
  const short* __restrict__ hT, const int* __restrict__ ei,
  const float* __restrict__ wig,
  const short* __restrict__ w1t, const short* __restrict__ togA,
  const short* __restrict__ fgA, const short* __restrict__ w0eT,
  const float* __restrict__ adot,
  const short* __restrict__ rfS, float* __restrict__ asum,
  float* __restrict__ agg)
{
  __shared__ __align__(16) short SH[7312];
  float* wigL  = (float*)&SH[4608];
  float* gateL = (float*)&SH[7168];
  float* ahead = (float*)&SH[7296];
  const int tid = threadIdx.x;
  const int wv = tid>>6, lane = tid&63, lo = lane&15, q = lane>>4;
  const int e = blockIdx.x;
  const int src = ei[e], dst = ei[NE+e];

  // stage hcatT[128][32] (src rows 0..63, dst rows 64..127) via global_load_lds
  {
    const char* g0 = (const char*)(hT + (size_t)src*2048) + wv*1024 + lane*16;
    const char* g1 = (const char*)(hT + (size_t)dst*2048) + wv*1024 + lane*16;
    gload_lds16(g0, (char*)SH + wv*1024);
    gload_lds16(g1, (char*)SH + 4096 + wv*1024);
  }
  // zero region-A tail not covered by staging (kills uninit-LDS NaN reads)
  {
    const s16x4 z4 = {0,0,0,0};
    if (tid < 128) *(s16x4*)&SH[4096 + tid*4] = z4;
  }
  // stage wigner f32 coalesced into wigL (region B; dead until msg phase)
  {
    const float* w = wig + (size_t)e*625;
    for (int idx=tid; idx<625; idx+=256) wigL[idx] = w[idx];
  }
  // rfS -> regs
  s16x4 rvp[2][2];
  {
    const short* rrow = rfS + (size_t)e*640;
#pragma unroll
    for (int t=0;t<2;t++){
      int c0 = (2*wv+t)*16 + q*4;
#pragma unroll
      for (int nt=0;nt<2;nt++){
        int i = nt*16 + lo;
        int l = (i>=16)?4:((i>=9)?3:((i>=4)?2:((i>=1)?1:0)));
        rvp[t][nt] = *(const s16x4*)&rrow[l*128 + c0];
      }
    }
  }
  asm volatile("s_waitcnt vmcnt(0)" ::: "memory");
  __syncthreads();                                   // [#1] hcatT + wigL ready

  // build all 4 wigner frags from LDS via packed converts
  const bfrag8 wz = {0,0,0,0,0,0,0,0};
  bfrag8 wb0, wtb0, wb1 = wz, wtb1 = wz;
  {
    union { unsigned u[4]; bfrag8 f; } A, B;
#pragma unroll
    for (int k=0;k<4;k++){
      int j0 = q*8 + 2*k, j1 = j0+1;
      float a0 = (j0<25) ? wigL[lo*25+j0] : 0.f;
      float a1 = (j1<25) ? wigL[lo*25+j1] : 0.f;
      float b0 = (j0<25) ? wigL[j0*25+lo] : 0.f;
      float b1 = (j1<25) ? wigL[j1*25+lo] : 0.f;
      A.u[k] = cvtpk(a0,a1);
      B.u[k] = cvtpk(b0,b1);
    }
    wb0 = A.f; wtb0 = B.f;
  }
  if (lo < 9){
    union { unsigned u[4]; bfrag8 f; } A, B;
#pragma unroll
    for (int k=0;k<4;k++){
      int j0 = q*8 + 2*k, j1 = j0+1;
      float a0 = (j0<25) ? wigL[(16+lo)*25+j0] : 0.f;
      float a1 = (j1<25) ? wigL[(16+lo)*25+j1] : 0.f;
      float b0 = (j0<25) ? wigL[j0*25+16+lo] : 0.f;
      float b1 = (j1<25) ? wigL[j1*25+16+lo] : 0.f;
      A.u[k] = cvtpk(a0,a1);
      B.u[k] = cvtpk(b0,b1);
    }
    wb1 = A.f; wtb1 = B.f;
  }

  // rot1 MFMA: D[c][i] = sum_j hcatT[c][j] * W[i][j]
  f32x4 xacc[2][2];
  {
    const f32x4 zf = {0.f,0.f,0.f,0.f};
#pragma unroll
    for (int t=0;t<2;t++){
      int c = (2*wv+t)*16 + lo;
      bfrag8 a = *(const bfrag8*)&SH[c*32 + ((q ^ ((c>>1)&3))<<3)];
      xacc[t][0] = __builtin_amdgcn_mfma_f32_16x16x32_bf16(a, wb0, zf, 0,0,0);
      xacc[t][1] = __builtin_amdgcn_mfma_f32_16x16x32_bf16(a, wb1, zf, 0,0,0);
    }
  }
  __syncthreads();                                   // [#2] hcatT + wigL dead
  // epilogue: xeB[i][c] = xe * r
#pragma unroll
  for (int t=0;t<2;t++){
    int c0 = (2*wv+t)*16 + q*4;
#pragma unroll
    for (int nt=0;nt<2;nt++){
      int i = nt*16 + lo;
      s16x4 rv = rvp[t][nt];
      *(s16x4*)&SH[i*136 + c0] =
        pk4(xacc[t][nt][0]*b2f(rv[0]), xacc[t][nt][1]*b2f(rv[1]),
            xacc[t][nt][2]*b2f(rv[2]), xacc[t][nt][3]*b2f(rv[3]));
    }
  }
  __syncthreads();                                   // [#3] xeB ready

  // extra: D = w0eT(192x128) @ broadcast(xe row0) -> alpha heads + gate
  {
    bfrag8 xb[4];
#pragma unroll
    for (int kt=0;kt<4;kt++) xb[kt] = *(const bfrag8*)&SH[kt*32 + q*8];  // row 0, bcast
    const f32x4 zf = {0.f,0.f,0.f,0.f};
#pragma unroll
    for (int t=0;t<3;t++){
      const int mt = wv*3 + t;     // 12 tiles: 0..7 heads, 8..11 gate
      f32x4 acc = zf;
#pragma unroll
      for (int kt=0;kt<4;kt++){
        bfrag8 a = *(const bfrag8*)&w0eT[(mt*16+lo)*128 + kt*32 + q*8];
        acc = __builtin_amdgcn_mfma_f32_16x16x32_bf16(a, xb[kt], acc, 0,0,0);
      }
      if (mt < 8){
        float s = 0.f;
#pragma unroll
        for (int r=0;r<4;r++) s += silu_f(acc[r]) * adot[mt*16 + q*4 + r];
        s += __shfl_xor(s, 16);
        s += __shfl_xor(s, 32);
        float eh = __expf(s);
        if (lane==0){
          ahead[mt] = eh;
          unsafeAtomicAdd(&asum[(size_t)dst*8 + mt], eh);
        }
      } else if (lo==0){
        int g0 = mt*16 - 128 + q*4;
#pragma unroll
        for (int r=0;r<4;r++) gateL[g0+r] = silu_f(acc[r]);
      }
    }
  }
  // msg: msgs[hh][i] (wave-local rows; overwrites wigL region — past barrier #3)
  {
    const int hh = wv*16 + lo;
    const f32x4 zf = {0.f,0.f,0.f,0.f};
    f32x4 acc[2] = {zf,zf};
#pragma unroll
    for (int kt=0;kt<4;kt++){
      bfrag8 b = *(const bfrag8*)&w1t[hh*136 + kt*32 + q*8];
#pragma unroll
      for (int t=0;t<2;t++){
        bfrag8 a = *(const bfrag8*)&SH[(t*16+lo)*136 + kt*32 + q*8];
        acc[t] = __builtin_amdgcn_mfma_f32_16x16x32_bf16(a, b, acc[t], 0,0,0);
      }
    }
#pragma unroll
    for (int t=0;t<2;t++)
      *(s16x4*)&SH[4608 + hh*40 + t*16 + q*4] =
        pk4(acc[t][0], acc[t][1], acc[t][2], acc[t][3]);
  }
  __syncthreads();                 // [#4] xeB dead (sg aliases it); ahead/gateL visible

  // grid fwd: sg[hh][g] @ region A
  {
    const int hh = wv*16 + lo;
    bfrag8 b = *(const bfrag8*)&SH[4608 + hh*40 + q*8];
    const f32x4 zf = {0.f,0.f,0.f,0.f};
    f32x4 acc[3] = {zf,zf,zf};
#pragma unroll
    for (int t=0;t<3;t++){
      bfrag8 a = *(const bfrag8*)&togA[(t*16+lo)*40 + q*8];
      acc[t] = __builtin_amdgcn_mfma_f32_16x16x32_bf16(a, b, acc[t], 0,0,0);
    }
#pragma unroll
    for (int t=0;t<3;t++)
      *(s16x4*)&SH[hh*72 + t*16 + q*4] =
        pk4(silu_f(acc[t][0]), silu_f(acc[t][1]), silu_f(acc[t][2]), silu_f(acc[t][3]));
  }
  // grid bwd: msg2[hh][j] (row0 <- gate), * exp(alpha)
  {
    const int hh = wv*16 + lo;
    const f32x4 zf = {0.f,0.f,0.f,0.f};
    f32x4 acc[2] = {zf,zf};
#pragma unroll
    for (int kt=0;kt<2;kt++){
      bfrag8 b = *(const bfrag8*)&SH[hh*72 + kt*32 + q*8];
#pragma unroll
      for (int t=0;t<2;t++){
        bfrag8 a = *(const bfrag8*)&fgA[(t*16+lo)*72 + kt*32 + q*8];
        acc[t] = __builtin_amdgcn_mfma_f32_16x16x32_bf16(a, b, acc[t], 0,0,0);
      }
    }
    float ah = ahead[hh>>3];
#pragma unroll
    for (int t=0;t<2;t++){
      float vv[4];
#pragma unroll
      for (int r=0;r<4;r++){
        int j = t*16 + q*4 + r;
        vv[r] = ((j==0) ? gateL[hh] : acc[t][r]) * ah;
      }
      *(s16x4*)&SH[4608 + hh*40 + t*16 + q*4] = pk4(vv[0], vv[1], vv[2], vv[3]);
    }
  }
  // rot2 + atomic scatter (wT frags in VGPRs; random dst order decorrelates targets)
  {
    const int hh = wv*16 + lo;
    bfrag8 b = *(const bfrag8*)&SH[4608 + hh*40 + q*8];
    const f32x4 zf = {0.f,0.f,0.f,0.f};
    f32x4 acc0 = __builtin_amdgcn_mfma_f32_16x16x32_bf16(wtb0, b, zf, 0,0,0);
    f32x4 acc1 = __builtin_amdgcn_mfma_f32_16x16x32_bf16(wtb1, b, zf, 0,0,0);
    float* aggp = agg + (size_t)dst*1600;
#pragma unroll
    for (int r=0;r<4;r++){
      int i0 = q*4 + r;                       // 0..15 < 25 always
      unsafeAtomicAdd(&aggp[i0*64 + hh], acc0[r]);
      int i1 = 16 + q*4 + r;
      if (i1 < 25) unsafeAtomicAdd(&aggp[i1*64 + hh], acc1[r]);
    }
  }
}

// ---------------- K4: node update + FFN, MFMA ----------------
__global__ __launch_bounds__(256,4) void k_node(
  const float* __restrict__ x, const float* __restrict__ aggin,
  const float* __restrict__ asum,
  const short* __restrict__ projT, const float* __restrict__ gamma2,
  const float* __restrict__ glw, const float* __restrict__ glb,
  const short* __restrict__ fw1T, const float* __restrict__ fb1,
  const short* __restrict__ fw2T, const float* __restrict__ fb2,
  const short* __restrict__ togA, const short* __restrict__ fgA,
  float* __restrict__ out)
{
  __shared__ __align__(16) short P[19072];
  float* xF    = (float*)P;
  short* sgB   = P + 4352;
  short* hh2B  = P + 4352;
  short* f1B   = P + 13568;
  short* aggB  = P + 13568;
  short* xgB   = P + 13568;
  float* invc  = ((float*)P) + 9344;
  float* gateF = ((float*)P) + 9408;
  const int tid = threadIdx.x;
  const int wv = tid>>6, lane = tid&63, lo = lane&15, q = lane>>4;
  const int n = blockIdx.x;
  const s16x4 z4 = {0,0,0,0};

  for (int idx=tid; idx<400; idx+=256){
    int i = idx>>4, k = idx&15;
    float sc = 1.f/(asum[(size_t)n*8 + (k>>1)] + 1e-8f);
    const float4 v = *(const float4*)(aggin + (size_t)n*1600 + (size_t)idx*4);
    *(s16x4*)&aggB[i*72 + k*4] = pk4(v.x*sc, v.y*sc, v.z*sc, v.w*sc);
  }
  for (int idx=tid; idx<126; idx+=256)
    *(s16x4*)&hh2B[25*72 + idx*4] = z4;
  for (int idx=tid; idx<512; idx+=256){
    int f = idx>>2, gg = 48 + (idx&3)*4;
    *(s16x4*)&sgB[f*72 + gg] = z4;
  }
  __syncthreads();

  {
    f32x4 zf={0.f,0.f,0.f,0.f}; f32x4 acc[2]={zf,zf};
    const int c = wv*16 + lo;
#pragma unroll
    for (int kt=0;kt<2;kt++){
      bfrag8 b = *(const bfrag8*)&projT[c*64 + kt*32 + q*8];
#pragma unroll
      for (int t=0;t<2;t++){
        bfrag8 a = *(const bfrag8*)&aggB[(t*16+lo)*72 + kt*32 + q*8];
        acc[t] = __builtin_amdgcn_mfma_f32_16x16x32_bf16(a,b,acc[t],0,0,0);
      }
    }
#pragma unroll
    for (int t=0;t<2;t++)
#pragma unroll
      for (int r=0;r<4;r++){
        int i = t*16 + q*4 + r;
        if (i<25) xF[i*68+c] = acc[t][r] + x[(size_t)n*1600 + i*64 + c];
      }
  }
  __syncthreads();
  if (tid<64){
    float ss=0.f;
#pragma unroll
    for (int i=0;i<25;i++){ float v = xF[i*68+tid]; ss += v*v; }
    invc[tid] = gamma2[tid]*rsqrtf(ss*(1.f/25.f)+1e-6f);
  }
  __syncthreads();
  for (int idx=tid; idx<800; idx+=256){
    int i = idx>>5, c2 = (idx&31)*2;
    *(unsigned*)&hh2B[i*72+c2] =
      cvtpk(xF[i*68+c2]*invc[c2], xF[i*68+c2+1]*invc[c2+1]);
  }
  if (tid<128){
    float a = glb[tid];
#pragma unroll 8
    for (int c=0;c<64;c++) a += xF[c]*invc[c]*glw[c*128+tid];
    gateF[tid] = silu_f(a);
  }
  __syncthreads();

  {
    f32x4 zf={0.f,0.f,0.f,0.f}; f32x4 acc[2][2]={{zf,zf},{zf,zf}};
#pragma unroll
    for (int kt=0;kt<2;kt++){
      bfrag8 a0 = *(const bfrag8*)&hh2B[(lo)*72 + kt*32 + q*8];
      bfrag8 a1 = *(const bfrag8*)&hh2B[(16+lo)*72 + kt*32 + q*8];
#pragma unroll
      for (int s=0;s<2;s++){
        int f = wv*32 + s*16 + lo;
        bfrag8 b = *(const bfrag8*)&fw1T[f*64 + kt*32 + q*8];
        acc[0][s] = __builtin_amdgcn_mfma_f32_16x16x32_bf16(a0,b,acc[0][s],0,0,0);
        acc[1][s] = __builtin_amdgcn_mfma_f32_16x16x32_bf16(a1,b,acc[1][s],0,0,0);
      }
    }
#pragma unroll
    for (int s=0;s<2;s++){
      int f = wv*32 + s*16 + lo;
      float bb = fb1[f];
#pragma unroll
      for (int t=0;t<2;t++){
        float vv[4];
#pragma unroll
        for (int r=0;r<4;r++){
          int i = t*16+q*4+r;
          vv[r] = acc[t][s][r] + (i==0 ? bb : 0.f);
        }
        *(s16x4*)&f1B[f*40 + t*16 + q*4] = pk4(vv[0], vv[1], vv[2], vv[3]);
      }
    }
  }
  __syncthreads();

  {
    f32x4 zf={0.f,0.f,0.f,0.f}; f32x4 acc[3][2]={{zf,zf},{zf,zf},{zf,zf}};
    bfrag8 a0 = *(const bfrag8*)&togA[(lo)*40 + q*8];
    bfrag8 a1 = *(const bfrag8*)&togA[(16+lo)*40 + q*8];
    bfrag8 a2 = *(const bfrag8*)&togA[(32+lo)*40 + q*8];
#pragma unroll
    for (int s=0;s<2;s++){
      int f = wv*32 + s*16 + lo;
      bfrag8 b = *(const bfrag8*)&f1B[f*40 + q*8];
      acc[0][s] = __builtin_amdgcn_mfma_f32_16x16x32_bf16(a0,b,acc[0][s],0,0,0);
      acc[1][s] = __builtin_amdgcn_mfma_f32_16x16x32_bf16(a1,b,acc[1][s],0,0,0);
      acc[2][s] = __builtin_amdgcn_mfma_f32_16x16x32_bf16(a2,b,acc[2][s],0,0,0);
    }
#pragma unroll
    for (int s=0;s<2;s++){
      int f = wv*32 + s*16 + lo;
#pragma unroll
      for (int t=0;t<3;t++)
        *(s16x4*)&sgB[f*72 + t*16 + q*4] =
          pk4(silu_f(acc[t][s][0]), silu_f(acc[t][s][1]),
              silu_f(acc[t][s][2]), silu_f(acc[t][s][3]));
    }
  }
  __syncthreads();

  {
    f32x4 zf={0.f,0.f,0.f,0.f}; f32x4 acc[2][2]={{zf,zf},{zf,zf}};
#pragma unroll
    for (int kt=0;kt<2;kt++){
#pragma unroll
      for (int t=0;t<2;t++){
        bfrag8 b = *(const bfrag8*)&fgA[(t*16+lo)*72 + kt*32 + q*8];
#pragma unroll
        for (int s=0;s<2;s++){
          bfrag8 a = *(const bfrag8*)&sgB[(wv*32+s*16+lo)*72 + kt*32 + q*8];
          acc[s][t] = __builtin_amdgcn_mfma_f32_16x16x32_bf16(a,b,acc[s][t],0,0,0);
        }
      }
    }
#pragma unroll
    for (int s=0;s<2;s++){
      int f0 = wv*32 + s*16 + q*4;
#pragma unroll
      for (int t=0;t<2;t++){
        int j = t*16 + lo;
        float vv[4];
#pragma unroll
        for (int r=0;r<4;r++)
          vv[r] = (j==0) ? gateF[f0+r] : acc[s][t][r];
        *(s16x4*)&xgB[j*136 + f0] = pk4(vv[0], vv[1], vv[2], vv[3]);
      }
    }
  }
  __syncthreads();

  {
    f32x4 zf={0.f,0.f,0.f,0.f}; f32x4 acc[2]={zf,zf};
    const int c = wv*16 + lo;
#pragma unroll
    for (int kt=0;kt<4;kt++){
      bfrag8 b = *(const bfrag8*)&fw2T[c*128 + kt*32 + q*8];
#pragma unroll
      for (int t=0;t<2;t++){
        bfrag8 a = *(const bfrag8*)&xgB[(t*16+lo)*136 + kt*32 + q*8];
        acc[t] = __builtin_amdgcn_mfma_f32_16x16x32_bf16(a,b,acc[t],0,0,0);
      }
    }
    float bb = fb2[c];
#pragma unroll
    for (int t=0;t<2;t++)
#pragma unroll
      for (int r=0;r<4;r++){
        int i = t*16 + q*4 + r;
        if (i<25)
          out[(size_t)n*1600 + i*64 + c] = xF[i*68+c] + acc[t][r] + (i==0 ? bb : 0.f);
      }
  }
}

extern "C" void kernel_launch(void* const* d_in, const int* in_sizes, int n_in,
                              void* d_out, int out_size, void* d_ws, size_t ws_size,
                              hipStream_t stream) {
  (void)in_sizes; (void)n_in; (void)ws_size;
  const float* x     = (const float*)d_in[0];
  const int*   ei    = (const int*)d_in[1];
  const int*   an    = (const int*)d_in[2];
  const float* edist = (const float*)d_in[3];
  const float* wig   = (const float*)d_in[4];
  const float* stab  = (const float*)d_in[5];
  const float* ttab  = (const float*)d_in[6];
  const float* rw1   = (const float*)d_in[7];
  const float* rb1   = (const float*)d_in[8];
  const float* rw2   = (const float*)d_in[9];
  const float* rb2   = (const float*)d_in[10];
  const float* rw3   = (const float*)d_in[11];
  const float* rb3   = (const float*)d_in[12];
  const float* W1    = (const float*)d_in[13];
  const float* w0e   = (const float*)d_in[14];
  const float* adot  = (const float*)d_in[15];
  const float* tog   = (const float*)d_in[16];
  const float* fromg = (const float*)d_in[17];
  const float* proj  = (const float*)d_in[18];
  const float* g1    = (const float*)d_in[19];
  const float* g2    = (const float*)d_in[20];
  const float* glw   = (const float*)d_in[21];
  const float* glb   = (const float*)d_in[22];
  const float* fw1   = (const float*)d_in[23];
  const float* fb1   = (const float*)d_in[24];
  const float* fw2   = (const float*)d_in[25];
  const float* fb2   = (const float*)d_in[26];
  float* out = (float*)d_out;

  char* wsb = (char*)d_ws;
  short* hT     = (short*)(wsb);                    // 40,960,000 B
  short* rfS    = (short*)(wsb + 40960000);         // 64,000,000 B
  float* asum   = (float*)(wsb + 104960000);        // 320,000 B
  short* w1t    = (short*)(wsb + 105280000);        // 17,408
  short* togA   = (short*)(wsb + 105297408);        // 3,840
  short* fgA    = (short*)(wsb + 105301248);        // 4,608
  short* projT  = (short*)(wsb + 105305856);        // 8,192
  short* fw1T   = (short*)(wsb + 105314048);        // 16,384
  short* fw2T   = (short*)(wsb + 105330432);        // 16,384
  short* rw1T   = (short*)(wsb + 105346816);        // 12,288
  short* rw2T   = (short*)(wsb + 105359104);        // 8,192
  short* rw3T   = (short*)(wsb + 105367296);        // 81,920
  short* w0eT   = (short*)(wsb + 105449216);        // 49,152

  hipMemsetAsync(asum, 0, (size_t)NN*8*sizeof(float), stream);
  hipMemsetAsync(d_out, 0, (size_t)out_size*sizeof(float), stream);  // d_out = agg

  k_wprep<<<32, 256, 0, stream>>>(W1, tog, fromg, proj, fw1, fw2, rw1, rw2, rw3, w0e,
                                  w1t, togA, fgA, projT, fw1T, fw2T,
                                  rw1T, rw2T, rw3T, w0eT);
  k_rms1  <<<(NN*64+255)/256, 256, 0, stream>>>(x, g1, hT);
  k_radial<<<(NE+31)/32, 256, 0, stream>>>(ei, an, edist, stab, ttab,
                                           rw1T, rb1, rw2T, rb2, rw3T, rb3, rfS);
  k_edge  <<<NE, 256, 0, stream>>>(hT, ei, wig, w1t, togA, fgA, w0eT, adot,
                                   rfS, asum, out);
  k_node  <<<NN, 256, 0, stream>>>(x, out, asum, projT, g2, glw, glb,
                                   fw1T, fb1, fw2T, fb2, togA, fgA, out);
}

// Round 10
// 957.931 us; speedup vs baseline: 1.3358x; 1.0037x over previous
//
#include <hip/hip_runtime.h>
#include <hip/hip_bf16.h>

#define NN 10000
#define NE 50000

typedef __attribute__((ext_vector_type(8))) short bfrag8;  // 8 bf16 = 4 VGPR (MFMA A/B)
typedef __attribute__((ext_vector_type(4))) short s16x4;   // 4 bf16 = b64 store
typedef __attribute__((ext_vector_type(8))) short s16x8;   // 8 bf16 = b128 store
typedef __attribute__((ext_vector_type(4))) float f32x4;   // MFMA C/D

__device__ __forceinline__ float silu_f(float v){ return v / (1.0f + __expf(-v)); }
__device__ __forceinline__ short f2b(float f){           // f32 -> bf16 RNE (prep only)
  unsigned u = __float_as_uint(f);
  u += 0x7fffu + ((u>>16)&1u);
  return (short)(u>>16);
}
__device__ __forceinline__ float b2f(short s){
  return __uint_as_float(((unsigned)(unsigned short)s)<<16);
}
// packed f32x2 -> bf16x2 (RNE) via HIP intrinsic (compiler lowers to native cvt)
__device__ __forceinline__ unsigned cvtpk(float a, float b){
  union { __hip_bfloat162 h2; unsigned u; } x;
  x.h2 = __float22bfloat162_rn(make_float2(a,b));   // .x -> low 16, .y -> high 16
  return x.u;
}
__device__ __forceinline__ s16x4 pk4(float a, float b, float c, float d){
  union { unsigned u[2]; s16x4 s; } x;
  x.u[0] = cvtpk(a,b); x.u[1] = cvtpk(c,d);
  return x.s;
}
// async global->LDS: per-lane global addr, wave-uniform LDS base, lane*16 dest
__device__ __forceinline__ void gload_lds16(const void* g, void* l){
  __builtin_amdgcn_global_load_lds(
      (const __attribute__((address_space(1))) void*)g,
      (__attribute__((address_space(3))) void*)l, 16, 0, 0);
}

// ---------------- K0: hT[n][c][j] = bf16(rmsnorm(x)) transposed+swizzled ----------------
__global__ __launch_bounds__(256) void k_rms1(const float* __restrict__ x,
                                              const float* __restrict__ gamma,
                                              short* __restrict__ hT){
  int idx = blockIdx.x*256 + threadIdx.x;
  if (idx >= NN*64) return;
  int n = idx>>6, c = idx&63;
  const float* xp = x + (size_t)n*1600 + c;
  float v[25]; float ss = 0.f;
#pragma unroll
  for (int i=0;i<25;i++){ v[i] = xp[i*64]; ss += v[i]*v[i]; }
  float inv = gamma[c] * rsqrtf(ss*(1.f/25.f) + 1e-6f);
  short* hp = hT + (size_t)n*2048 + c*32;
  const int sw = (c>>1)&3;
#pragma unroll
  for (int s=0;s<4;s++){
    union { unsigned u[4]; s16x8 s8; } o;
#pragma unroll
    for (int k=0;k<4;k++){
      int j0 = s*8 + 2*k, j1 = j0+1;
      float a = (j0<25) ? v[j0]*inv : 0.f;
      float b = (j1<25) ? v[j1]*inv : 0.f;
      o.u[k] = cvtpk(a,b);
    }
    *(s16x8*)(hp + ((s ^ sw)<<3)) = o.s8;
  }
}

// ------------- Kprep: weights -> MFMA bf16 layouts -------------
__global__ void k_wprep(const float* __restrict__ W1, const float* __restrict__ tog,
                        const float* __restrict__ fromg, const float* __restrict__ proj,
                        const float* __restrict__ fw1, const float* __restrict__ fw2,
                        const float* __restrict__ rw1, const float* __restrict__ rw2,
                        const float* __restrict__ rw3, const float* __restrict__ w0e,
                        const float* __restrict__ glw,
                        short* __restrict__ w1t, short* __restrict__ togA,
                        short* __restrict__ fgA, short* __restrict__ projT,
                        short* __restrict__ fw1T, short* __restrict__ fw2T,
                        short* __restrict__ rw1T, short* __restrict__ rw2T,
                        short* __restrict__ rw3T, short* __restrict__ w0eT,
                        short* __restrict__ glwT){
  int t0 = blockIdx.x*blockDim.x + threadIdx.x;
  int stride = gridDim.x*blockDim.x;
  for (int idx=t0; idx<64*136; idx+=stride){
    int hh = idx/136, k = idx-136*hh;
    w1t[idx] = (k<128) ? f2b(W1[k*64+hh]) : (short)0;
  }
  for (int idx=t0; idx<48*40; idx+=stride){
    int g = idx/40, i = idx-40*g;
    togA[idx] = (g<36 && i<25) ? f2b(tog[g*25+i]) : (short)0;
  }
  for (int idx=t0; idx<32*72; idx+=stride){
    int j = idx/72, g = idx-72*j;
    fgA[idx] = (j<25 && g<36) ? f2b(fromg[j*36+g]) : (short)0;
  }
  for (int idx=t0; idx<64*64; idx+=stride){   // projT[c][k] = proj[k][c]
    int c = idx>>6, k = idx&63;
    projT[idx] = f2b(proj[k*64+c]);
  }
  for (int idx=t0; idx<128*64; idx+=stride){  // fw1T[f][c] = fw1[c][f]
    int f = idx>>6, c = idx&63;
    fw1T[idx] = f2b(fw1[c*128+f]);
  }
  for (int idx=t0; idx<64*128; idx+=stride){  // fw2T[c][f] = fw2[f][c]
    int c = idx>>7, f = idx&127;
    fw2T[idx] = f2b(fw2[f*64+c]);
  }
  for (int idx=t0; idx<64*96; idx+=stride){   // rw1T[n][k] = rw1[k][n]
    int n = idx/96, k = idx-96*n;
    rw1T[idx] = f2b(rw1[k*64+n]);
  }
  for (int idx=t0; idx<64*64; idx+=stride){   // rw2T[n][k] = rw2[k][n]
    int n = idx>>6, k = idx&63;
    rw2T[idx] = f2b(rw2[k*64+n]);
  }
  for (int idx=t0; idx<640*64; idx+=stride){  // rw3T[n][k] = rw3[k][n]
    int n = idx>>6, k = idx&63;
    rw3T[idx] = f2b(rw3[(size_t)k*640+n]);
  }
  for (int idx=t0; idx<192*128; idx+=stride){ // w0eT[m][c] = w0e[c][m]
    int m = idx>>7, c = idx&127;
    w0eT[idx] = f2b(w0e[c*192+m]);
  }
  for (int idx=t0; idx<128*64; idx+=stride){  // glwT[f][c] = glw[c][f]
    int f = idx>>6, c = idx&63;
    glwT[idx] = f2b(glw[c*128+f]);
  }
}

// ---------------- K1: radial MLP, MFMA, 32 edges/block ----------------
__global__ __launch_bounds__(256,4) void k_radial(
  const int* __restrict__ ei, const int* __restrict__ an,
  const float* __restrict__ edist,
  const float* __restrict__ stab, const float* __restrict__ ttab,
  const short* __restrict__ rw1T, const float* __restrict__ rb1,
  const short* __restrict__ rw2T, const float* __restrict__ rb2,
  const short* __restrict__ rw3T, const float* __restrict__ rb3,
  short* __restrict__ rfS)
{
  __shared__ __align__(16) short SP[7936];
  const int tid = threadIdx.x;
  const int wv = tid>>6, lane = tid&63, lo = lane&15, q = lane>>4;
  const int e0 = blockIdx.x*32;
  {
    int e = tid>>3;
    int ee = min(e0+e, NE-1);
    int srcE = ei[ee], dstE = ei[NE+ee];
    const float* dp = edist + (size_t)ee*32;
    const float* sp = stab + (size_t)an[srcE]*32;
    const float* tp = ttab + (size_t)an[dstE]*32;
    int kb = tid&7;
#pragma unroll
    for (int it=0; it<12; ++it){
      int k = kb + it*8;
      float v = (k<32) ? dp[k] : (k<64 ? sp[k-32] : tp[k-64]);
      SP[e*104+k] = f2b(v);
    }
  }
  __syncthreads();
  {
    f32x4 zf={0.f,0.f,0.f,0.f}; f32x4 acc[2]={zf,zf};
#pragma unroll
    for (int kt=0;kt<3;kt++){
      bfrag8 a = *(const bfrag8*)&rw1T[(wv*16+lo)*96 + kt*32 + q*8];
#pragma unroll
      for (int et=0;et<2;et++){
        bfrag8 b = *(const bfrag8*)&SP[(et*16+lo)*104 + kt*32 + q*8];
        acc[et] = __builtin_amdgcn_mfma_f32_16x16x32_bf16(a,b,acc[et],0,0,0);
      }
    }
    int n1 = wv*16 + q*4;
    const float4 bb = *(const float4*)&rb1[n1];
#pragma unroll
    for (int et=0;et<2;et++){
      *(s16x4*)&SP[3328 + (et*16+lo)*72 + n1] =
        pk4(silu_f(acc[et][0]+bb.x), silu_f(acc[et][1]+bb.y),
            silu_f(acc[et][2]+bb.z), silu_f(acc[et][3]+bb.w));
    }
  }
  __syncthreads();
  {
    f32x4 zf={0.f,0.f,0.f,0.f}; f32x4 acc[2]={zf,zf};
#pragma unroll
    for (int kt=0;kt<2;kt++){
      bfrag8 a = *(const bfrag8*)&rw2T[(wv*16+lo)*64 + kt*32 + q*8];
#pragma unroll
      for (int et=0;et<2;et++){
        bfrag8 b = *(const bfrag8*)&SP[3328 + (et*16+lo)*72 + kt*32 + q*8];
        acc[et] = __builtin_amdgcn_mfma_f32_16x16x32_bf16(a,b,acc[et],0,0,0);
      }
    }
    int n2 = wv*16 + q*4;
    const float4 bb = *(const float4*)&rb2[n2];
#pragma unroll
    for (int et=0;et<2;et++){
      *(s16x4*)&SP[5632 + (et*16+lo)*72 + n2] =
        pk4(silu_f(acc[et][0]+bb.x), silu_f(acc[et][1]+bb.y),
            silu_f(acc[et][2]+bb.z), silu_f(acc[et][3]+bb.w));
    }
  }
  __syncthreads();
  {
    bfrag8 bfr[2][2];
#pragma unroll
    for (int et=0;et<2;et++)
#pragma unroll
      for (int kt=0;kt<2;kt++)
        bfr[et][kt] = *(const bfrag8*)&SP[5632 + (et*16+lo)*72 + kt*32 + q*8];
    for (int mi=0; mi<10; ++mi){
      int n3base = (wv + mi*4)*16;
      f32x4 zf={0.f,0.f,0.f,0.f}; f32x4 acc[2]={zf,zf};
#pragma unroll
      for (int kt=0;kt<2;kt++){
        bfrag8 a = *(const bfrag8*)&rw3T[(size_t)(n3base+lo)*64 + kt*32 + q*8];
        acc[0] = __builtin_amdgcn_mfma_f32_16x16x32_bf16(a,bfr[0][kt],acc[0],0,0,0);
        acc[1] = __builtin_amdgcn_mfma_f32_16x16x32_bf16(a,bfr[1][kt],acc[1],0,0,0);
      }
      int n3 = n3base + q*4;
      const float4 bb = *(const float4*)&rb3[n3];
#pragma unroll
      for (int et=0;et<2;et++){
        int e = e0 + et*16 + lo;
        if (e < NE){
          *(s16x4*)&rfS[(size_t)e*640 + n3] =
            pk4(acc[et][0]+bb.x, acc[et][1]+bb.y, acc[et][2]+bb.z, acc[et][3]+bb.w);
        }
      }
    }
  }
}

// ---------------- K3: MFMA edge kernel, edge-parallel, natural order ----------------
// LDS shorts: region A [0,4608): hcatT[128][32]swz -> xeB[32][136] -> sg[64][72]
//             region B [4608,7168): wigL f32[25][32] padded (start..barrier#2)
//                                    -> msgs/msg2[64][40]
//             gateL f32[64] @ [7168,7296); ahead f32[8] @ [7296,7312)
__global__ __launch_bounds__(256,8) void k_edge(
  const short* __restrict__ hT, const int* __restrict__ ei,
  const float* __restrict__ wig,
  const short* __restrict__ w1t, const short* __restrict__ togA,
  const short* __restrict__ fgA, const short* __restrict__ w0eT,
  const float* __restrict__ adot,
  const short* __restrict__ rfS, float* __restrict__ asum,
  float* __restrict__ agg)
{
  __shared__ __align__(16) short SH[7312];
  float* wigL  = (float*)&SH[4608];
  float* gateL = (float*)&SH[7168];
  float* ahead = (float*)&SH[7296];
  const int tid = threadIdx.x;
  const int wv = tid>>6, lane = tid&63, lo = lane&15, q = lane>>4;
  const int e = blockIdx.x;
  const int src = ei[e], dst = ei[NE+e];

  // stage hcatT[128][32] (src rows 0..63, dst rows 64..127) via global_load_lds
  {
    const char* g0 = (const char*)(hT + (size_t)src*2048) + wv*1024 + lane*16;
    const char* g1 = (const char*)(hT + (size_t)dst*2048) + wv*1024 + lane*16;
    gload_lds16(g0, (char*)SH + wv*1024);
    gload_lds16(g1, (char*)SH + 4096 + wv*1024);
  }
  // zero region-A tail not covered by staging (kills uninit-LDS NaN reads)
  {
    const s16x4 z4 = {0,0,0,0};
    if (tid < 128) *(s16x4*)&SH[4096 + tid*4] = z4;
  }
  // stage wigner f32 PADDED [25][32] into wigL (cols 25-31 zeroed -> maskless wb)
  {
    const float* w = wig + (size_t)e*625;
    for (int idx=tid; idx<800; idx+=256){
      int i = idx>>5, j = idx&31;
      wigL[idx] = (j<25) ? w[i*25+j] : 0.f;
    }
  }
  // rfS -> regs
  s16x4 rvp[2][2];
  {
    const short* rrow = rfS + (size_t)e*640;
#pragma unroll
    for (int t=0;t<2;t++){
      int c0 = (2*wv+t)*16 + q*4;
#pragma unroll
      for (int nt=0;nt<2;nt++){
        int i = nt*16 + lo;
        int l = (i>=16)?4:((i>=9)?3:((i>=4)?2:((i>=1)?1:0)));
        rvp[t][nt] = *(const s16x4*)&rrow[l*128 + c0];
      }
    }
  }
  asm volatile("s_waitcnt vmcnt(0)" ::: "memory");
  __syncthreads();                                   // [#1] hcatT + wigL ready

  // build all 4 wigner frags: wb via aligned b128 reads (maskless), wtb scalar
  const bfrag8 wz = {0,0,0,0,0,0,0,0};
  bfrag8 wb0, wtb0, wb1 = wz, wtb1 = wz;
  {
    const float4 ra = *(const float4*)&wigL[lo*32 + q*8];
    const float4 rb = *(const float4*)&wigL[lo*32 + q*8 + 4];
    union { unsigned u[4]; bfrag8 f; } A;
    A.u[0]=cvtpk(ra.x,ra.y); A.u[1]=cvtpk(ra.z,ra.w);
    A.u[2]=cvtpk(rb.x,rb.y); A.u[3]=cvtpk(rb.z,rb.w);
    wb0 = A.f;
    union { unsigned u[4]; bfrag8 f; } B;
#pragma unroll
    for (int k=0;k<4;k++){
      int j0 = q*8 + 2*k, j1 = j0+1;
      float b0 = (j0<25) ? wigL[j0*32+lo] : 0.f;
      float b1 = (j1<25) ? wigL[j1*32+lo] : 0.f;
      B.u[k] = cvtpk(b0,b1);
    }
    wtb0 = B.f;
  }
  if (lo < 9){
    const float4 ra = *(const float4*)&wigL[(16+lo)*32 + q*8];
    const float4 rb = *(const float4*)&wigL[(16+lo)*32 + q*8 + 4];
    union { unsigned u[4]; bfrag8 f; } A;
    A.u[0]=cvtpk(ra.x,ra.y); A.u[1]=cvtpk(ra.z,ra.w);
    A.u[2]=cvtpk(rb.x,rb.y); A.u[3]=cvtpk(rb.z,rb.w);
    wb1 = A.f;
    union { unsigned u[4]; bfrag8 f; } B;
#pragma unroll
    for (int k=0;k<4;k++){
      int j0 = q*8 + 2*k, j1 = j0+1;
      float b0 = (j0<25) ? wigL[j0*32+16+lo] : 0.f;
      float b1 = (j1<25) ? wigL[j1*32+16+lo] : 0.f;
      B.u[k] = cvtpk(b0,b1);
    }
    wtb1 = B.f;
  }

  // rot1 MFMA: D[c][i] = sum_j hcatT[c][j] * W[i][j]
  f32x4 xacc[2][2];
  {
    const f32x4 zf = {0.f,0.f,0.f,0.f};
#pragma unroll
    for (int t=0;t<2;t++){
      int c = (2*wv+t)*16 + lo;
      bfrag8 a = *(const bfrag8*)&SH[c*32 + ((q ^ ((c>>1)&3))<<3)];
      xacc[t][0] = __builtin_amdgcn_mfma_f32_16x16x32_bf16(a, wb0, zf, 0,0,0);
      xacc[t][1] = __builtin_amdgcn_mfma_f32_16x16x32_bf16(a, wb1, zf, 0,0,0);
    }
  }
  __syncthreads();                                   // [#2] hcatT + wigL dead
  // epilogue: xeB[i][c] = xe * r
#pragma unroll
  for (int t=0;t<2;t++){
    int c0 = (2*wv+t)*16 + q*4;
#pragma unroll
    for (int nt=0;nt<2;nt++){
      int i = nt*16 + lo;
      s16x4 rv = rvp[t][nt];
      *(s16x4*)&SH[i*136 + c0] =
        pk4(xacc[t][nt][0]*b2f(rv[0]), xacc[t][nt][1]*b2f(rv[1]),
            xacc[t][nt][2]*b2f(rv[2]), xacc[t][nt][3]*b2f(rv[3]));
    }
  }
  __syncthreads();                                   // [#3] xeB ready

  // extra: D = w0eT(192x128) @ broadcast(xe row0) -> alpha heads + gate
  {
    bfrag8 xb[4];
#pragma unroll
    for (int kt=0;kt<4;kt++) xb[kt] = *(const bfrag8*)&SH[kt*32 + q*8];  // row 0, bcast
    const f32x4 zf = {0.f,0.f,0.f,0.f};
#pragma unroll
    for (int t=0;t<3;t++){
      const int mt = wv*3 + t;     // 12 tiles: 0..7 heads, 8..11 gate
      f32x4 acc = zf;
#pragma unroll
      for (int kt=0;kt<4;kt++){
        bfrag8 a = *(const bfrag8*)&w0eT[(mt*16+lo)*128 + kt*32 + q*8];
        acc = __builtin_amdgcn_mfma_f32_16x16x32_bf16(a, xb[kt], acc, 0,0,0);
      }
      if (mt < 8){
        float s = 0.f;
#pragma unroll
        for (int r=0;r<4;r++) s += silu_f(acc[r]) * adot[mt*16 + q*4 + r];
        s += __shfl_xor(s, 16);
        s += __shfl_xor(s, 32);
        float eh = __expf(s);
        if (lane==0){
          ahead[mt] = eh;
          unsafeAtomicAdd(&asum[(size_t)dst*8 + mt], eh);
        }
      } else if (lo==0){
        int g0 = mt*16 - 128 + q*4;
#pragma unroll
        for (int r=0;r<4;r++) gateL[g0+r] = silu_f(acc[r]);
      }
    }
  }
  // msg: msgs[hh][i] (wave-local rows; overwrites wigL region — past barrier #3)
  {
    const int hh = wv*16 + lo;
    const f32x4 zf = {0.f,0.f,0.f,0.f};
    f32x4 acc[2] = {zf,zf};
#pragma unroll
    for (int kt=0;kt<4;kt++){
      bfrag8 b = *(const bfrag8*)&w1t[hh*136 + kt*32 + q*8];
#pragma unroll
      for (int t=0;t<2;t++){
        bfrag8 a = *(const bfrag8*)&SH[(t*16+lo)*136 + kt*32 + q*8];
        acc[t] = __builtin_amdgcn_mfma_f32_16x16x32_bf16(a, b, acc[t], 0,0,0);
      }
    }
#pragma unroll
    for (int t=0;t<2;t++)
      *(s16x4*)&SH[4608 + hh*40 + t*16 + q*4] =
        pk4(acc[t][0], acc[t][1], acc[t][2], acc[t][3]);
  }
  __syncthreads();                 // [#4] xeB dead (sg aliases it); ahead/gateL visible

  // grid fwd: sg[hh][g] @ region A
  {
    const int hh = wv*16 + lo;
    bfrag8 b = *(const bfrag8*)&SH[4608 + hh*40 + q*8];
    const f32x4 zf = {0.f,0.f,0.f,0.f};
    f32x4 acc[3] = {zf,zf,zf};
#pragma unroll
    for (int t=0;t<3;t++){
      bfrag8 a = *(const bfrag8*)&togA[(t*16+lo)*40 + q*8];
      acc[t] = __builtin_amdgcn_mfma_f32_16x16x32_bf16(a, b, acc[t], 0,0,0);
    }
#pragma unroll
    for (int t=0;t<3;t++)
      *(s16x4*)&SH[hh*72 + t*16 + q*4] =
        pk4(silu_f(acc[t][0]), silu_f(acc[t][1]), silu_f(acc[t][2]), silu_f(acc[t][3]));
  }
  // grid bwd: msg2[hh][j] (row0 <- gate), * exp(alpha)
  {
    const int hh = wv*16 + lo;
    const f32x4 zf = {0.f,0.f,0.f,0.f};
    f32x4 acc[2] = {zf,zf};
#pragma unroll
    for (int kt=0;kt<2;kt++){
      bfrag8 b = *(const bfrag8*)&SH[hh*72 + kt*32 + q*8];
#pragma unroll
      for (int t=0;t<2;t++){
        bfrag8 a = *(const bfrag8*)&fgA[(t*16+lo)*72 + kt*32 + q*8];
        acc[t] = __builtin_amdgcn_mfma_f32_16x16x32_bf16(a, b, acc[t], 0,0,0);
      }
    }
    float ah = ahead[hh>>3];
#pragma unroll
    for (int t=0;t<2;t++){
      float vv[4];
#pragma unroll
      for (int r=0;r<4;r++){
        int j = t*16 + q*4 + r;
        vv[r] = ((j==0) ? gateL[hh] : acc[t][r]) * ah;
      }
      *(s16x4*)&SH[4608 + hh*40 + t*16 + q*4] = pk4(vv[0], vv[1], vv[2], vv[3]);
    }
  }
  // rot2 + atomic scatter (wT frags in VGPRs; random dst order decorrelates targets)
  {
    const int hh = wv*16 + lo;
    bfrag8 b = *(const bfrag8*)&SH[4608 + hh*40 + q*8];
    const f32x4 zf = {0.f,0.f,0.f,0.f};
    f32x4 acc0 = __builtin_amdgcn_mfma_f32_16x16x32_bf16(wtb0, b, zf, 0,0,0);
    f32x4 acc1 = __builtin_amdgcn_mfma_f32_16x16x32_bf16(wtb1, b, zf, 0,0,0);
    float* aggp = agg + (size_t)dst*1600;
#pragma unroll
    for (int r=0;r<4;r++){
      int i0 = q*4 + r;                       // 0..15 < 25 always
      unsafeAtomicAdd(&aggp[i0*64 + hh], acc0[r]);
      int i1 = 16 + q*4 + r;
      if (i1 < 25) unsafeAtomicAdd(&aggp[i1*64 + hh], acc1[r]);
    }
  }
}

// ---------------- K4: node update + FFN, MFMA ----------------
__global__ __launch_bounds__(256,4) void k_node(
  const float* __restrict__ x, const float* __restrict__ aggin,
  const float* __restrict__ asum,
  const short* __restrict__ projT, const float* __restrict__ gamma2,
  const short* __restrict__ glwT, const float* __restrict__ glb,
  const short* __restrict__ fw1T, const float* __restrict__ fb1,
  const short* __restrict__ fw2T, const float* __restrict__ fb2,
  const short* __restrict__ togA, const short* __restrict__ fgA,
  float* __restrict__ out)
{
  __shared__ __align__(16) short P[19072];
  float* xF    = (float*)P;
  short* sgB   = P + 4352;
  short* hh2B  = P + 4352;
  short* f1B   = P + 13568;
  short* aggB  = P + 13568;
  short* xgB   = P + 13568;
  float* invc  = ((float*)P) + 9344;
  float* gateF = ((float*)P) + 9408;
  const int tid = threadIdx.x;
  const int wv = tid>>6, lane = tid&63, lo = lane&15, q = lane>>4;
  const int n = blockIdx.x;
  const s16x4 z4 = {0,0,0,0};

  for (int idx=tid; idx<400; idx+=256){
    int i = idx>>4, k = idx&15;
    float sc = 1.f/(asum[(size_t)n*8 + (k>>1)] + 1e-8f);
    const float4 v = *(const float4*)(aggin + (size_t)n*1600 + (size_t)idx*4);
    *(s16x4*)&aggB[i*72 + k*4] = pk4(v.x*sc, v.y*sc, v.z*sc, v.w*sc);
  }
  for (int idx=tid; idx<126; idx+=256)
    *(s16x4*)&hh2B[25*72 + idx*4] = z4;
  for (int idx=tid; idx<512; idx+=256){
    int f = idx>>2, gg = 48 + (idx&3)*4;
    *(s16x4*)&sgB[f*72 + gg] = z4;
  }
  __syncthreads();

  {
    f32x4 zf={0.f,0.f,0.f,0.f}; f32x4 acc[2]={zf,zf};
    const int c = wv*16 + lo;
#pragma unroll
    for (int kt=0;kt<2;kt++){
      bfrag8 b = *(const bfrag8*)&projT[c*64 + kt*32 + q*8];
#pragma unroll
      for (int t=0;t<2;t++){
        bfrag8 a = *(const bfrag8*)&aggB[(t*16+lo)*72 + kt*32 + q*8];
        acc[t] = __builtin_amdgcn_mfma_f32_16x16x32_bf16(a,b,acc[t],0,0,0);
      }
    }
#pragma unroll
    for (int t=0;t<2;t++)
#pragma unroll
      for (int r=0;r<4;r++){
        int i = t*16 + q*4 + r;
        if (i<25) xF[i*68+c] = acc[t][r] + x[(size_t)n*1600 + i*64 + c];
      }
  }
  __syncthreads();
  if (tid<64){
    float ss=0.f;
#pragma unroll
    for (int i=0;i<25;i++){ float v = xF[i*68+tid]; ss += v*v; }
    invc[tid] = gamma2[tid]*rsqrtf(ss*(1.f/25.f)+1e-6f);
  }
  __syncthreads();
  for (int idx=tid; idx<800; idx+=256){
    int i = idx>>5, c2 = (idx&31)*2;
    *(unsigned*)&hh2B[i*72+c2] =
      cvtpk(xF[i*68+c2]*invc[c2], xF[i*68+c2+1]*invc[c2+1]);
  }
  __syncthreads();

  { // gate = silu(h0 @ glw + glb) via broadcast MFMA (hh2B row0 ready)
    bfrag8 xb0 = *(const bfrag8*)&hh2B[q*8];        // h0[k], bcast over n
    bfrag8 xb1 = *(const bfrag8*)&hh2B[32 + q*8];
    const f32x4 zf = {0.f,0.f,0.f,0.f};
#pragma unroll
    for (int t=0;t<2;t++){
      const int mt = wv*2 + t;                      // 8 tiles x 16 f
      f32x4 acc = zf;
      bfrag8 a0 = *(const bfrag8*)&glwT[(mt*16+lo)*64 + q*8];
      bfrag8 a1 = *(const bfrag8*)&glwT[(mt*16+lo)*64 + 32 + q*8];
      acc = __builtin_amdgcn_mfma_f32_16x16x32_bf16(a0, xb0, acc, 0,0,0);
      acc = __builtin_amdgcn_mfma_f32_16x16x32_bf16(a1, xb1, acc, 0,0,0);
      if (lo == 0){
#pragma unroll
        for (int r=0;r<4;r++){
          int f = mt*16 + q*4 + r;
          gateF[f] = silu_f(acc[r] + glb[f]);
        }
      }
    }
  }
  {
    f32x4 zf={0.f,0.f,0.f,0.f}; f32x4 acc[2][2]={{zf,zf},{zf,zf}};
#pragma unroll
    for (int kt=0;kt<2;kt++){
      bfrag8 a0 = *(const bfrag8*)&hh2B[(lo)*72 + kt*32 + q*8];
      bfrag8 a1 = *(const bfrag8*)&hh2B[(16+lo)*72 + kt*32 + q*8];
#pragma unroll
      for (int s=0;s<2;s++){
        int f = wv*32 + s*16 + lo;
        bfrag8 b = *(const bfrag8*)&fw1T[f*64 + kt*32 + q*8];
        acc[0][s] = __builtin_amdgcn_mfma_f32_16x16x32_bf16(a0,b,acc[0][s],0,0,0);
        acc[1][s] = __builtin_amdgcn_mfma_f32_16x16x32_bf16(a1,b,acc[1][s],0,0,0);
      }
    }
#pragma unroll
    for (int s=0;s<2;s++){
      int f = wv*32 + s*16 + lo;
      float bb = fb1[f];
#pragma unroll
      for (int t=0;t<2;t++){
        float vv[4];
#pragma unroll
        for (int r=0;r<4;r++){
          int i = t*16+q*4+r;
          vv[r] = acc[t][s][r] + (i==0 ? bb : 0.f);
        }
        *(s16x4*)&f1B[f*40 + t*16 + q*4] = pk4(vv[0], vv[1], vv[2], vv[3]);
      }
    }
  }
  __syncthreads();

  {
    f32x4 zf={0.f,0.f,0.f,0.f}; f32x4 acc[3][2]={{zf,zf},{zf,zf},{zf,zf}};
    bfrag8 a0 = *(const bfrag8*)&togA[(lo)*40 + q*8];
    bfrag8 a1 = *(const bfrag8*)&togA[(16+lo)*40 + q*8];
    bfrag8 a2 = *(const bfrag8*)&togA[(32+lo)*40 + q*8];
#pragma unroll
    for (int s=0;s<2;s++){
      int f = wv*32 + s*16 + lo;
      bfrag8 b = *(const bfrag8*)&f1B[f*40 + q*8];
      acc[0][s] = __builtin_amdgcn_mfma_f32_16x16x32_bf16(a0,b,acc[0][s],0,0,0);
      acc[1][s] = __builtin_amdgcn_mfma_f32_16x16x32_bf16(a1,b,acc[1][s],0,0,0);
      acc[2][s] = __builtin_amdgcn_mfma_f32_16x16x32_bf16(a2,b,acc[2][s],0,0,0);
    }
#pragma unroll
    for (int s=0;s<2;s++){
      int f = wv*32 + s*16 + lo;
#pragma unroll
      for (int t=0;t<3;t++)
        *(s16x4*)&sgB[f*72 + t*16 + q*4] =
          pk4(silu_f(acc[t][s][0]), silu_f(acc[t][s][1]),
              silu_f(acc[t][s][2]), silu_f(acc[t][s][3]));
    }
  }
  __syncthreads();

  {
    f32x4 zf={0.f,0.f,0.f,0.f}; f32x4 acc[2][2]={{zf,zf},{zf,zf}};
#pragma unroll
    for (int kt=0;kt<2;kt++){
#pragma unroll
      for (int t=0;t<2;t++){
        bfrag8 b = *(const bfrag8*)&fgA[(t*16+lo)*72 + kt*32 + q*8];
#pragma unroll
        for (int s=0;s<2;s++){
          bfrag8 a = *(const bfrag8*)&sgB[(wv*32+s*16+lo)*72 + kt*32 + q*8];
          acc[s][t] = __builtin_amdgcn_mfma_f32_16x16x32_bf16(a,b,acc[s][t],0,0,0);
        }
      }
    }
#pragma unroll
    for (int s=0;s<2;s++){
      int f0 = wv*32 + s*16 + q*4;
#pragma unroll
      for (int t=0;t<2;t++){
        int j = t*16 + lo;
        float vv[4];
#pragma unroll
        for (int r=0;r<4;r++)
          vv[r] = (j==0) ? gateF[f0+r] : acc[s][t][r];
        *(s16x4*)&xgB[j*136 + f0] = pk4(vv[0], vv[1], vv[2], vv[3]);
      }
    }
  }
  __syncthreads();

  {
    f32x4 zf={0.f,0.f,0.f,0.f}; f32x4 acc[2]={zf,zf};
    const int c = wv*16 + lo;
#pragma unroll
    for (int kt=0;kt<4;kt++){
      bfrag8 b = *(const bfrag8*)&fw2T[c*128 + kt*32 + q*8];
#pragma unroll
      for (int t=0;t<2;t++){
        bfrag8 a = *(const bfrag8*)&xgB[(t*16+lo)*136 + kt*32 + q*8];
        acc[t] = __builtin_amdgcn_mfma_f32_16x16x32_bf16(a,b,acc[t],0,0,0);
      }
    }
    float bb = fb2[c];
#pragma unroll
    for (int t=0;t<2;t++)
#pragma unroll
      for (int r=0;r<4;r++){
        int i = t*16 + q*4 + r;
        if (i<25)
          out[(size_t)n*1600 + i*64 + c] = xF[i*68+c] + acc[t][r] + (i==0 ? bb : 0.f);
      }
  }
}

extern "C" void kernel_launch(void* const* d_in, const int* in_sizes, int n_in,
                              void* d_out, int out_size, void* d_ws, size_t ws_size,
                              hipStream_t stream) {
  (void)in_sizes; (void)n_in; (void)ws_size;
  const float* x     = (const float*)d_in[0];
  const int*   ei    = (const int*)d_in[1];
  const int*   an    = (const int*)d_in[2];
  const float* edist = (const float*)d_in[3];
  const float* wig   = (const float*)d_in[4];
  const float* stab  = (const float*)d_in[5];
  const float* ttab  = (const float*)d_in[6];
  const float* rw1   = (const float*)d_in[7];
  const float* rb1   = (const float*)d_in[8];
  const float* rw2   = (const float*)d_in[9];
  const float* rb2   = (const float*)d_in[10];
  const float* rw3   = (const float*)d_in[11];
  const float* rb3   = (const float*)d_in[12];
  const float* W1    = (const float*)d_in[13];
  const float* w0e   = (const float*)d_in[14];
  const float* adot  = (const float*)d_in[15];
  const float* tog   = (const float*)d_in[16];
  const float* fromg = (const float*)d_in[17];
  const float* proj  = (const float*)d_in[18];
  const float* g1    = (const float*)d_in[19];
  const float* g2    = (const float*)d_in[20];
  const float* glw   = (const float*)d_in[21];
  const float* glb   = (const float*)d_in[22];
  const float* fw1   = (const float*)d_in[23];
  const float* fb1   = (const float*)d_in[24];
  const float* fw2   = (const float*)d_in[25];
  const float* fb2   = (const float*)d_in[26];
  float* out = (float*)d_out;

  char* wsb = (char*)d_ws;
  short* hT     = (short*)(wsb);                    // 40,960,000 B
  short* rfS    = (short*)(wsb + 40960000);         // 64,000,000 B
  float* asum   = (float*)(wsb + 104960000);        // 320,000 B
  short* w1t    = (short*)(wsb + 105280000);        // 17,408
  short* togA   = (short*)(wsb + 105297408);        // 3,840
  short* fgA    = (short*)(wsb + 105301248);        // 4,608
  short* projT  = (short*)(wsb + 105305856);        // 8,192
  short* fw1T   = (short*)(wsb + 105314048);        // 16,384
  short* fw2T   = (short*)(wsb + 105330432);        // 16,384
  short* rw1T   = (short*)(wsb + 105346816);        // 12,288
  short* rw2T   = (short*)(wsb + 105359104);        // 8,192
  short* rw3T   = (short*)(wsb + 105367296);        // 81,920
  short* w0eT   = (short*)(wsb + 105449216);        // 49,152
  short* glwT   = (short*)(wsb + 105498368);        // 16,384

  hipMemsetAsync(asum, 0, (size_t)NN*8*sizeof(float), stream);
  hipMemsetAsync(d_out, 0, (size_t)out_size*sizeof(float), stream);  // d_out = agg

  k_wprep<<<32, 256, 0, stream>>>(W1, tog, fromg, proj, fw1, fw2, rw1, rw2, rw3, w0e,
                                  glw,
                                  w1t, togA, fgA, projT, fw1T, fw2T,
                                  rw1T, rw2T, rw3T, w0eT, glwT);
  k_rms1  <<<(NN*64+255)/256, 256, 0, stream>>>(x, g1, hT);
  k_radial<<<(NE+31)/32, 256, 0, stream>>>(ei, an, edist, stab, ttab,
                                           rw1T, rb1, rw2T, rb2, rw3T, rb3, rfS);
  k_edge  <<<NE, 256, 0, stream>>>(hT, ei, wig, w1t, togA, fgA, w0eT, adot,
                                   rfS, asum, out);
  k_node  <<<NN, 256, 0, stream>>>(x, out, asum, projT, g2, glwT, glb,
                                   fw1T, fb1, fw2T, fb2, togA, fgA, out);
}